// Round 5
// baseline (133.698 us; speedup 1.0000x reference)
//
#include <hip/hip_runtime.h>
#include <math.h>
#include <limits.h>

#define EPSF 1e-6f
#define THR 0.5f
#define PUSH_W 1.0f
#define PULL_W 1.0f

constexpr int BN = 2048;    // proposals per batch
constexpr int BG = 64;      // gt boxes per batch

__device__ __forceinline__ float iou_box(float4 a, float4 b) {
  float aa = (a.z - a.x) * (a.w - a.y);
  float ab = (b.z - b.x) * (b.w - b.y);
  float w = fmaxf(fminf(a.z, b.z) - fmaxf(a.x, b.x), 0.f);
  float h = fmaxf(fminf(a.w, b.w) - fmaxf(a.y, b.y), 0.f);
  float inter = w * h;
  return inter / (aa + ab - inter + EPSF);
}

// -------------------------------------------------- K1: rank-by-count sort
__global__ __launch_bounds__(256) void k1_sort(
    const int* __restrict__ gti_all, const float* __restrict__ gtb_all,
    const float* __restrict__ prop_all,
    float4* __restrict__ boxs, float* __restrict__ pers,
    short* __restrict__ gtss, float* __restrict__ scs)
{
  const int b = blockIdx.x & 7;        // batch -> XCD-ish
  const int rg = blockIdx.x >> 3;      // row group
  const int tid = threadIdx.x;
  __shared__ unsigned long long key[BN];   // 16 KB

  const float* P = prop_all + (size_t)b * BN * 5;
  const int* gti = gti_all + b * BN;
  const float* GB = gtb_all + b * BG * 4;

  for (int k = 0; k < 8; ++k) {
    int j = tid + k * 256;
    unsigned bits = __float_as_uint(P[j * 5 + 4]);
    key[j] = ((unsigned long long)bits << 32) | (unsigned)(BN - 1 - j);
  }
  __syncthreads();

  const int r = rg * 256 + tid;
  const unsigned long long myk = key[r];
  int rank = 0;
  const ulonglong2* K2 = (const ulonglong2*)key;
#pragma unroll 8
  for (int j = 0; j < BN / 2; ++j) {
    ulonglong2 kk = K2[j];
    rank += (kk.x > myk) ? 1 : 0;
    rank += (kk.y > myk) ? 1 : 0;
  }

  int idx = (BN - 1) - (int)(myk & 0xffffffffu);
  float x1 = P[idx * 5 + 0], y1 = P[idx * 5 + 1];
  float x2 = P[idx * 5 + 2], y2 = P[idx * 5 + 3];
  float s = __uint_as_float((unsigned)(myk >> 32));
  int g = gti[idx];
  float4 bx = make_float4(x1, y1, x2, y2);
  boxs[b * BN + rank] = bx;
  scs[b * BN + rank] = s;
  gtss[b * BN + rank] = (short)g;
  float pv = 0.f;
  if (g >= 0) {
    float4 gb = make_float4(GB[g * 4 + 0], GB[g * 4 + 1], GB[g * 4 + 2], GB[g * 4 + 3]);
    float i2 = iou_box(gb, bx);
    pv = -logf(EPSF + i2) * s;
  }
  pers[b * BN + rank] = pv;
}

// ------------------------------------------------------------- K2: adjacency
__global__ __launch_bounds__(256) void k2_adj(
    const float4* __restrict__ boxs, unsigned* __restrict__ adj)
{
  const int b = blockIdx.x & 7;
  const int rg = blockIdx.x >> 3;
  const int tid = threadIdx.x;
  __shared__ float4 bs[BN];     // 32 KB

  const float4* B = boxs + b * BN;
  for (int k = 0; k < 8; ++k) bs[tid + k * 256] = B[tid + k * 256];
  __syncthreads();

  const int row = rg * 64 + (tid >> 2);
  const int q = tid & 3;
  float4 rb = bs[row];
  unsigned* arow = adj + ((size_t)b * BN + row) * 64;
#pragma unroll
  for (int wi = 0; wi < 16; ++wi) {
    int w = q * 16 + wi;
    int j0 = w * 32;
    unsigned bits = 0;
#pragma unroll
    for (int jj = 0; jj < 32; ++jj) {
      float i2 = iou_box(rb, bs[j0 + jj]);
      bits |= (i2 > THR) ? (1u << jj) : 0u;
    }
    arow[w] = bits;
  }
}

// ------------------------------------- K3a: serial greedy resolve (1 wave/batch)
__global__ __launch_bounds__(64) void k3a_resolve(
    const short* __restrict__ gtss, const unsigned* __restrict__ adj,
    unsigned* __restrict__ pm_g, int* __restrict__ fpr_g,
    unsigned short* __restrict__ ev_g, int* __restrict__ meta_g,
    float* __restrict__ qs_g, int* __restrict__ qc_g, unsigned* __restrict__ hp_g)
{
  const int b = blockIdx.x;
  const int lane = threadIdx.x;       // 0..63
  __shared__ unsigned short plist[BN];  // 4 KB
  __shared__ unsigned pm_s[64];
  __shared__ int fpr_s[64];

  const unsigned* A = adj + (size_t)b * BN * 64;

  // active word for my lane (ranks lane*32 .. +31)
  unsigned act = 0;
  {
    const int* gp = (const int*)(gtss + b * BN);
#pragma unroll
    for (int k = 0; k < 16; ++k) {
      int v = gp[lane * 16 + k];
      if ((short)(v & 0xffff) >= 0)       act |= 1u << (2 * k);
      if ((short)(v >> 16) >= 0)          act |= 1u << (2 * k + 1);
    }
  }
  int npos = __popc(act);
  for (int o = 1; o < 64; o <<= 1) npos += __shfl_xor(npos, o);

  unsigned sup = 0;
  unsigned mypm = 0;
  int npick = 0, prevbase = 0, prevcnt = 0;
  uint2 diag = *(const uint2*)&A[(size_t)lane * 64 + 0];   // chunk 0 diag

  for (int c = 0; c < 32; ++c) {
    uint2 diagn = diag;
    if (c + 1 < 32)
      diagn = *(const uint2*)&A[(size_t)((c + 1) * 64 + lane) * 64 + 2 * (c + 1)];

    // apply previous chunk's pick rows to sup (32-wide batched loads)
    for (int t = 0; t < prevcnt; t += 32) {
      unsigned r[32];
#pragma unroll
      for (int k = 0; k < 32; ++k) {
        int idx = prevbase + t + k;
        int lim = prevbase + prevcnt - 1;
        if (idx > lim) idx = lim;
        r[k] = A[(size_t)plist[idx] * 64 + lane];
      }
      unsigned acc = 0;
#pragma unroll
      for (int k = 0; k < 32; ++k) acc |= r[k];
      sup |= acc;
    }

    // extract this chunk's candidate u64 (wave-uniform scalar state)
    unsigned as0 = act & ~sup;
    unsigned lo = __builtin_amdgcn_readlane(as0, 2 * c);
    unsigned hi = __builtin_amdgcn_readlane(as0, 2 * c + 1);
    unsigned long long cand = ((unsigned long long)hi << 32) | lo;
    unsigned long long pickw = 0;
    unsigned mlo = diag.x, mhi = diag.y;     // my diag row (lane = row in chunk)
    int cbase = npick;
    while (cand) {
      int bpos = (int)__ffsll(cand) - 1;
      pickw |= 1ull << bpos;
      unsigned rlo = __builtin_amdgcn_readlane(mlo, bpos);
      unsigned rhi = __builtin_amdgcn_readlane(mhi, bpos);
      cand &= ~(((unsigned long long)rhi << 32) | rlo);
      if (lane == 0) plist[npick] = (unsigned short)(c * 64 + bpos);
      npick++;
    }
    if (lane == 2 * c)     mypm |= (unsigned)(pickw & 0xffffffffull);
    if (lane == 2 * c + 1) mypm |= (unsigned)(pickw >> 32);
    prevbase = cbase; prevcnt = npick - cbase;
    diag = diagn;
  }

  pm_s[lane] = mypm;
  fpr_s[lane] = INT_MAX;
  __syncthreads();

  // prefix popcount, ev2rank, fpr
  int pre = 0;
  for (int w = 0; w < lane; ++w) pre += __popc(pm_s[w]);
  {
    unsigned w = mypm; int e = pre;
    while (w) {
      int bpos = __ffs(w) - 1; w &= w - 1;
      int rank = lane * 32 + bpos;
      ev_g[b * BN + e] = (unsigned short)rank;
      int g = (int)gtss[b * BN + rank];
      atomicMin(&fpr_s[g], rank);
      e++;
    }
  }
  __syncthreads();

  pm_g[b * 64 + lane] = mypm;
  fpr_g[b * 64 + lane] = fpr_s[lane];
  hp_g[b * 64 + lane] = 0u;
  if (lane == 0) {
    meta_g[b * 4 + 0] = npick;
    meta_g[b * 4 + 1] = 0;        // lastrem
    meta_g[b * 4 + 2] = npos;
  }
  // zero qs/qc
  for (int k = 0; k < 32; ++k) {
    int j = lane + k * 64;
    qs_g[b * BN + j] = 0.f;
    qc_g[b * BN + j] = 0;
  }
}

// ---------------------------- K3b: parallel per-box event contributions
__global__ __launch_bounds__(256) void k3b_events(
    const short* __restrict__ gtss, const float* __restrict__ pers,
    const unsigned* __restrict__ adj, const unsigned* __restrict__ pm_g,
    const int* __restrict__ fpr_g, int* __restrict__ meta_g,
    float* __restrict__ qs_g, int* __restrict__ qc_g, unsigned* __restrict__ hp_g)
{
  const int blk = blockIdx.x;       // 8 batches * 8 segments
  const int b = blk & 7;
  const int seg = blk >> 3;
  const int tid = threadIdx.x;
  __shared__ unsigned pm_s[64];
  __shared__ unsigned pre_s[64];
  __shared__ short gts_s[BN];       // 4 KB

  if (tid < 64) pm_s[tid] = pm_g[b * 64 + tid];
  for (int k = 0; k < 4; ++k)
    ((int*)gts_s)[tid + 256 * k] = ((const int*)(gtss + b * BN))[tid + 256 * k];
  __syncthreads();
  if (tid < 64) {
    int s = 0;
    for (int w = 0; w < tid; ++w) s += __popc(pm_s[w]);
    pre_s[tid] = (unsigned)s;
  }
  __syncthreads();

  const int j = seg * 256 + tid;
  const uint4* R = (const uint4*)(adj + ((size_t)b * BN + j) * 64);
  int frank = -1;
#pragma unroll
  for (int q = 0; q < 16; ++q) {
    uint4 r4 = R[q];
    unsigned m0 = r4.x & pm_s[q * 4 + 0];
    unsigned m1 = r4.y & pm_s[q * 4 + 1];
    unsigned m2 = r4.z & pm_s[q * 4 + 2];
    unsigned m3 = r4.w & pm_s[q * 4 + 3];
    if (frank < 0 && m0) frank = q * 128 +  0 + __ffs(m0) - 1;
    if (frank < 0 && m1) frank = q * 128 + 32 + __ffs(m1) - 1;
    if (frank < 0 && m2) frank = q * 128 + 64 + __ffs(m2) - 1;
    if (frank < 0 && m3) frank = q * 128 + 96 + __ffs(m3) - 1;
  }

  int gj = (int)gts_s[j];
  if (frank >= 0 && frank != j && gj >= 0) {
    int e = (int)pre_s[frank >> 5] + __popc(pm_s[frank >> 5] & ((1u << (frank & 31)) - 1u));
    int P = meta_g[b * 4 + 0];
    if (e == P - 1) atomicOr(&meta_g[b * 4 + 1], 1);
    int gt = (int)gts_s[frank];
    if (gj != gt) {
      atomicOr(&hp_g[b * 64 + (e >> 5)], 1u << (e & 31));
      if (fpr_g[b * 64 + gj] > frank) {
        atomicAdd(&qs_g[b * BN + e], pers[b * BN + j]);
        atomicAdd(&qc_g[b * BN + e], 1);
      }
    }
  }
}

// ---------------------------- K3c: event pass + final averaging (1 block)
__global__ __launch_bounds__(256) void k3c_loss(
    const float4* __restrict__ boxs, const float* __restrict__ scs,
    const short* __restrict__ gtss, const unsigned short* __restrict__ ev_g,
    const int* __restrict__ fpr_g, const int* __restrict__ meta_g,
    const float* __restrict__ qs_g, const int* __restrict__ qc_g,
    const unsigned* __restrict__ hp_g, float* __restrict__ out, int nb)
{
  const int tid = threadIdx.x;
  const int lane = tid & 63;
  const int wave = tid >> 6;
  __shared__ float redp[4][4];
  __shared__ float osum[2];
  if (tid == 0) { osum[0] = 0.f; osum[1] = 0.f; }

  for (int b = 0; b < nb; ++b) {
    const int P = meta_g[b * 4 + 0];
    const int lastrem = meta_g[b * 4 + 1];
    const int npos = meta_g[b * 4 + 2];
    float pull_l = 0.f, pcl = 0.f, push_l = 0.f, pshl = 0.f;
    for (int t = tid; t < P; t += 256) {
      int r = (int)ev_g[b * BN + t];
      int g = (int)gtss[b * BN + r];
      int fp = fpr_g[b * 64 + g];
      bool seen = (fp < r);
      bool hr = (t < P - 1) || (lastrem != 0);
      if (seen) {
        pcl += 1.f;
        if (hr) {
          float4 bA = boxs[b * BN + fp];
          float4 bB = boxs[b * BN + r];
          float io = iou_box(bA, bB);
          pull_l += -logf(1.f - THR + fmaxf(io, EPSF)) * scs[b * BN + r];
        }
      }
      if (hr && ((hp_g[b * 64 + (t >> 5)] >> (t & 31)) & 1u)) {
        pshl += 1.f;
        push_l += qs_g[b * BN + t] / ((float)qc_g[b * BN + t] + EPSF);
      }
    }
    for (int o = 1; o < 64; o <<= 1) {
      pull_l += __shfl_xor(pull_l, o);
      pcl    += __shfl_xor(pcl, o);
      push_l += __shfl_xor(push_l, o);
      pshl   += __shfl_xor(pshl, o);
    }
    if (lane == 0) { redp[wave][0] = pull_l; redp[wave][1] = pcl; redp[wave][2] = push_l; redp[wave][3] = pshl; }
    __syncthreads();
    if (tid == 0) {
      float Ps = 0.f, Pc = 0.f, Ss = 0.f, Sc = 0.f;
      for (int w = 0; w < 4; ++w) { Ps += redp[w][0]; Pc += redp[w][1]; Ss += redp[w][2]; Sc += redp[w][3]; }
      float gate = (npos > 1) ? 1.f : 0.f;
      osum[0] += gate * Ss / (Sc + EPSF);   // push
      osum[1] += gate * Ps / (Pc + EPSF);   // pull
    }
    __syncthreads();
  }
  if (tid == 0) {
    float inv = 1.f / (float)nb;
    out[0] = osum[0] * inv * PUSH_W;
    out[1] = osum[1] * inv * PULL_W;
  }
}

// =============================== fallback path (round-1 kernel, proven) =====
constexpr int NT = 256;
constexpr int PT = BN / NT;
constexpr int NW = NT / 64;

__global__ void nms_finalize_kernel(const float* __restrict__ bp, float* __restrict__ out, int nb) {
  if (threadIdx.x == 0 && blockIdx.x == 0) {
    float ps = 0.f, pl = 0.f;
    for (int b = 0; b < nb; ++b) { ps += bp[2 * b]; pl += bp[2 * b + 1]; }
    float inv = 1.f / (float)nb;
    out[0] = ps * inv * PUSH_W;
    out[1] = pl * inv * PULL_W;
  }
}

__global__ __launch_bounds__(NT) void nms_loss_kernel(
    const int* __restrict__ gti_all, const float* __restrict__ gtb_all,
    const float* __restrict__ prop_all, float* __restrict__ out_bp)
{
  const int b = blockIdx.x;
  const int tid = threadIdx.x;
  const int lane = tid & 63;
  const int wave = tid >> 6;

  __shared__ float4 box[BN];
  __shared__ float sc[BN];
  __shared__ float per[BN];
  __shared__ int gts[BN];
  __shared__ unsigned char act[BN];
  __shared__ int rec[BG];
  __shared__ float rs[NW];
  __shared__ int ri[NW];
  __shared__ int rrem[NW];
  __shared__ int rqc[NW];
  __shared__ float rqs[NW];
  __shared__ int rany[NW];
  __shared__ int sh_nact;
  __shared__ int sh_ig;
  __shared__ float4 sh_ibox;

  const int* gti = gti_all + b * BN;
  const float* GB = gtb_all + b * BG * 4;
  const float* P = prop_all + (size_t)b * BN * 5;

  int local_pos = 0;
  for (int k = 0; k < PT; ++k) {
    int j = tid + k * NT;
    float x1 = P[j * 5 + 0], y1 = P[j * 5 + 1];
    float x2 = P[j * 5 + 2], y2 = P[j * 5 + 3];
    float s = P[j * 5 + 4];
    box[j] = make_float4(x1, y1, x2, y2);
    sc[j] = s;
    int g = gti[j];
    gts[j] = g;
    unsigned char a = (g >= 0) ? 1 : 0;
    act[j] = a;
    local_pos += a;
    float pv = 0.f;
    if (g >= 0) {
      float4 gb = make_float4(GB[g * 4], GB[g * 4 + 1], GB[g * 4 + 2], GB[g * 4 + 3]);
      float i2 = iou_box(gb, make_float4(x1, y1, x2, y2));
      pv = -logf(EPSF + i2) * s;
    }
    per[j] = pv;
  }
  if (tid < BG) rec[tid] = -1;
  for (int off = 32; off; off >>= 1) local_pos += __shfl_down(local_pos, off);
  if (lane == 0) rrem[wave] = local_pos;
  __syncthreads();
  int n_pos = 0;
  if (tid == 0) {
    for (int w = 0; w < NW; ++w) n_pos += rrem[w];
    sh_nact = n_pos;
  }
  float pull_sum = 0.f, push_sum = 0.f, pull_cnt = 0.f, push_cnt = 0.f;
  int t0_hasrem = 0;
  __syncthreads();

  while (true) {
    int nact = sh_nact;
    if (nact <= 0) break;
    float bs = -INFINITY;
    int bi = BN;
    for (int k = 0; k < PT; ++k) {
      int j = tid + k * NT;
      if (act[j]) {
        float s = sc[j];
        if (s > bs || (s == bs && j < bi)) { bs = s; bi = j; }
      }
    }
    for (int off = 32; off; off >>= 1) {
      float os = __shfl_down(bs, off);
      int oi = __shfl_down(bi, off);
      if (os > bs || (os == bs && oi < bi)) { bs = os; bi = oi; }
    }
    if (lane == 0) { rs[wave] = bs; ri[wave] = bi; }
    __syncthreads();
    if (tid == 0) {
      float cs = rs[0]; int ci = ri[0];
      for (int w = 1; w < NW; ++w)
        if (rs[w] > cs || (rs[w] == cs && ri[w] < ci)) { cs = rs[w]; ci = ri[w]; }
      int i = ci;
      int ig = gts[i];
      act[i] = 0;
      t0_hasrem = (nact - 1 > 0);
      int r = rec[ig];
      if (r >= 0) {
        pull_cnt += 1.f;
        if (t0_hasrem) {
          float i2 = iou_box(box[r], box[i]);
          float m = fmaxf(i2, EPSF);
          pull_sum += -logf(1.f - THR + m) * sc[i];
        }
      } else {
        rec[ig] = i;
      }
      sh_ig = ig; sh_ibox = box[i];
    }
    __syncthreads();
    float4 ib = sh_ibox;
    int igx = sh_ig;
    int removed = 0, qcc = 0, anyp = 0;
    float qss = 0.f;
    for (int k = 0; k < PT; ++k) {
      int j = tid + k * NT;
      if (act[j]) {
        float i2 = iou_box(ib, box[j]);
        if (i2 > THR) {
          act[j] = 0;
          removed++;
          int gj = gts[j];
          if (gj != igx) {
            anyp = 1;
            if (rec[gj] < 0) { qcc++; qss += per[j]; }
          }
        }
      }
    }
    for (int off = 32; off; off >>= 1) {
      removed += __shfl_down(removed, off);
      qcc += __shfl_down(qcc, off);
      qss += __shfl_down(qss, off);
      anyp |= __shfl_down(anyp, off);
    }
    if (lane == 0) { rrem[wave] = removed; rqc[wave] = qcc; rqs[wave] = qss; rany[wave] = anyp; }
    __syncthreads();
    if (tid == 0) {
      int rm = 0, qct = 0, ap = 0; float qst = 0.f;
      for (int w = 0; w < NW; ++w) { rm += rrem[w]; qct += rqc[w]; qst += rqs[w]; ap |= rany[w]; }
      sh_nact = nact - 1 - rm;
      if (t0_hasrem && ap) {
        push_sum += qst / ((float)qct + EPSF);
        push_cnt += 1.f;
      }
    }
    __syncthreads();
  }

  if (tid == 0) {
    float gate = (n_pos > 1) ? 1.f : 0.f;
    out_bp[b * 2 + 0] = gate * push_sum / (push_cnt + EPSF);
    out_bp[b * 2 + 1] = gate * pull_sum / (pull_cnt + EPSF);
  }
}

// ============================================================== launch =====
extern "C" void kernel_launch(void* const* d_in, const int* in_sizes, int n_in,
                              void* d_out, int out_size, void* d_ws, size_t ws_size,
                              hipStream_t stream) {
  const int* gti = (const int*)d_in[1];
  const float* gtb = (const float*)d_in[2];
  const float* props = (const float*)d_in[3];
  float* out = (float*)d_out;
  const int nb = in_sizes[1] / BN;   // 8

  // ws layout (bytes)
  const size_t off_adj  = 0;                                    // nb*BN*64*4
  const size_t off_box  = off_adj  + (size_t)nb * BN * 64 * 4;  // nb*BN*16
  const size_t off_per  = off_box  + (size_t)nb * BN * 16;      // nb*BN*4
  const size_t off_sc   = off_per  + (size_t)nb * BN * 4;       // nb*BN*4
  const size_t off_qs   = off_sc   + (size_t)nb * BN * 4;       // nb*BN*4
  const size_t off_qc   = off_qs   + (size_t)nb * BN * 4;       // nb*BN*4
  const size_t off_gts  = off_qc   + (size_t)nb * BN * 4;       // nb*BN*2
  const size_t off_ev   = off_gts  + (size_t)nb * BN * 2;       // nb*BN*2
  const size_t off_pm   = off_ev   + (size_t)nb * BN * 2;       // nb*64*4
  const size_t off_fpr  = off_pm   + (size_t)nb * 64 * 4;       // nb*64*4
  const size_t off_hp   = off_fpr  + (size_t)nb * 64 * 4;       // nb*64*4
  const size_t off_meta = off_hp   + (size_t)nb * 64 * 4;       // nb*4*4
  const size_t needed   = off_meta + (size_t)nb * 4 * 4;

  if (ws_size >= needed && nb == 8) {
    char* ws = (char*)d_ws;
    unsigned* adj = (unsigned*)(ws + off_adj);
    float4* boxs = (float4*)(ws + off_box);
    float* pers = (float*)(ws + off_per);
    float* scs = (float*)(ws + off_sc);
    float* qs = (float*)(ws + off_qs);
    int* qc = (int*)(ws + off_qc);
    short* gtss = (short*)(ws + off_gts);
    unsigned short* ev = (unsigned short*)(ws + off_ev);
    unsigned* pm = (unsigned*)(ws + off_pm);
    int* fpr = (int*)(ws + off_fpr);
    unsigned* hp = (unsigned*)(ws + off_hp);
    int* meta = (int*)(ws + off_meta);

    k1_sort<<<nb * 8, 256, 0, stream>>>(gti, gtb, props, boxs, pers, gtss, scs);
    k2_adj<<<nb * 32, 256, 0, stream>>>(boxs, adj);
    k3a_resolve<<<nb, 64, 0, stream>>>(gtss, adj, pm, fpr, ev, meta, qs, qc, hp);
    k3b_events<<<nb * 8, 256, 0, stream>>>(gtss, pers, adj, pm, fpr, meta, qs, qc, hp);
    k3c_loss<<<1, 256, 0, stream>>>(boxs, scs, gtss, ev, fpr, meta, qs, qc, hp, out, nb);
  } else {
    float* bp = (float*)d_ws;
    nms_loss_kernel<<<nb, NT, 0, stream>>>(gti, gtb, props, bp);
    nms_finalize_kernel<<<1, 64, 0, stream>>>(bp, out, nb);
  }
}

// Round 6
// 129.908 us; speedup vs baseline: 1.0292x; 1.0292x over previous
//
#include <hip/hip_runtime.h>
#include <math.h>
#include <limits.h>

#define EPSF 1e-6f
#define THR 0.5f
#define PUSH_W 1.0f
#define PULL_W 1.0f

constexpr int BN = 2048;    // proposals per batch
constexpr int BG = 64;      // gt boxes per batch

__device__ __forceinline__ float iou_box(float4 a, float4 b) {
  float aa = (a.z - a.x) * (a.w - a.y);
  float ab = (b.z - b.x) * (b.w - b.y);
  float w = fmaxf(fminf(a.z, b.z) - fmaxf(a.x, b.x), 0.f);
  float h = fmaxf(fminf(a.w, b.w) - fmaxf(a.y, b.y), 0.f);
  float inter = w * h;
  return inter / (aa + ab - inter + EPSF);
}

// -------------------------------------------------- K1: rank-by-count sort
__global__ __launch_bounds__(256) void k1_sort(
    const int* __restrict__ gti_all, const float* __restrict__ gtb_all,
    const float* __restrict__ prop_all,
    float4* __restrict__ boxs, float* __restrict__ pers,
    short* __restrict__ gtss, float* __restrict__ scs)
{
  const int b = blockIdx.x & 7;        // batch
  const int rg = blockIdx.x >> 3;      // row group
  const int tid = threadIdx.x;
  __shared__ unsigned long long key[BN];   // 16 KB

  const float* P = prop_all + (size_t)b * BN * 5;
  const int* gti = gti_all + b * BN;
  const float* GB = gtb_all + b * BG * 4;

  for (int k = 0; k < 8; ++k) {
    int j = tid + k * 256;
    unsigned bits = __float_as_uint(P[j * 5 + 4]);
    key[j] = ((unsigned long long)bits << 32) | (unsigned)(BN - 1 - j);
  }
  __syncthreads();

  const int r = rg * 256 + tid;
  const unsigned long long myk = key[r];
  int rank = 0;
  const ulonglong2* K2 = (const ulonglong2*)key;
#pragma unroll 8
  for (int j = 0; j < BN / 2; ++j) {
    ulonglong2 kk = K2[j];
    rank += (kk.x > myk) ? 1 : 0;
    rank += (kk.y > myk) ? 1 : 0;
  }

  int idx = (BN - 1) - (int)(myk & 0xffffffffu);
  float x1 = P[idx * 5 + 0], y1 = P[idx * 5 + 1];
  float x2 = P[idx * 5 + 2], y2 = P[idx * 5 + 3];
  float s = __uint_as_float((unsigned)(myk >> 32));
  int g = gti[idx];
  float4 bx = make_float4(x1, y1, x2, y2);
  boxs[b * BN + rank] = bx;
  scs[b * BN + rank] = s;
  gtss[b * BN + rank] = (short)g;
  float pv = 0.f;
  if (g >= 0) {
    float4 gb = make_float4(GB[g * 4 + 0], GB[g * 4 + 1], GB[g * 4 + 2], GB[g * 4 + 3]);
    float i2 = iou_box(gb, bx);
    pv = -logf(EPSF + i2) * s;
  }
  pers[b * BN + rank] = pv;
}

// ------------------------------------------------------------- K2: adjacency
// rows-per-lane: lane owns a row (box in regs); wave sweeps a 256-col slice
// reading bs[j] at a wave-uniform address (LDS broadcast, conflict-free).
__global__ __launch_bounds__(512) void k2_adj(
    const float4* __restrict__ boxs, unsigned* __restrict__ adj)
{
  const int b = blockIdx.x & 7;
  const int rg = blockIdx.x >> 3;      // 0..31
  const int tid = threadIdx.x;         // 0..511
  const int lane = tid & 63;
  const int w = tid >> 6;              // wave 0..7 -> cols w*256..+256
  __shared__ float4 bs[BN];            // 32 KB

  const float4* B = boxs + b * BN;
  for (int k = tid; k < BN; k += 512) bs[k] = B[k];
  __syncthreads();

  const int row = rg * 64 + lane;
  const float4 rb = bs[row];
  const float aa = (rb.z - rb.x) * (rb.w - rb.y);

  unsigned out[8];
#pragma unroll
  for (int ww = 0; ww < 8; ++ww) {
    unsigned bits = 0;
    const int j0 = w * 256 + ww * 32;
#pragma unroll
    for (int jj = 0; jj < 32; ++jj) {
      float4 bj = bs[j0 + jj];                 // broadcast read
      float wd = fmaxf(fminf(rb.z, bj.z) - fmaxf(rb.x, bj.x), 0.f);
      float ht = fmaxf(fminf(rb.w, bj.w) - fmaxf(rb.y, bj.y), 0.f);
      float inter = wd * ht;
      if (inter > 0.f) {                       // exec-mask skip of IEEE div
        float ab = (bj.z - bj.x) * (bj.w - bj.y);
        float iou = inter / (aa + ab - inter + EPSF);
        bits |= (iou > THR) ? (1u << jj) : 0u;
      }
    }
    out[ww] = bits;
  }
  unsigned* arow = adj + ((size_t)b * BN + row) * 64 + w * 8;
  *(uint4*)(arow)     = make_uint4(out[0], out[1], out[2], out[3]);
  *(uint4*)(arow + 4) = make_uint4(out[4], out[5], out[6], out[7]);
}

// ------------------------------------- K3a: serial greedy resolve (1 wave/batch)
__global__ __launch_bounds__(64) void k3a_resolve(
    const short* __restrict__ gtss, const unsigned* __restrict__ adj,
    unsigned* __restrict__ pm_g, int* __restrict__ fpr_g,
    unsigned short* __restrict__ ev_g, int* __restrict__ meta_g,
    float* __restrict__ qs_g, int* __restrict__ qc_g, unsigned* __restrict__ hp_g)
{
  const int b = blockIdx.x;
  const int lane = threadIdx.x;       // 0..63
  __shared__ unsigned short plist[BN];  // 4 KB
  __shared__ unsigned pm_s[64];
  __shared__ int fpr_s[64];

  const unsigned* A = adj + (size_t)b * BN * 64;

  unsigned act = 0;
  {
    const int* gp = (const int*)(gtss + b * BN);
#pragma unroll
    for (int k = 0; k < 16; ++k) {
      int v = gp[lane * 16 + k];
      if ((short)(v & 0xffff) >= 0)       act |= 1u << (2 * k);
      if ((short)(v >> 16) >= 0)          act |= 1u << (2 * k + 1);
    }
  }
  int npos = __popc(act);
  for (int o = 1; o < 64; o <<= 1) npos += __shfl_xor(npos, o);

  unsigned sup = 0;
  unsigned mypm = 0;
  int npick = 0, prevbase = 0, prevcnt = 0;
  uint2 diag = *(const uint2*)&A[(size_t)lane * 64 + 0];   // chunk 0 diag

  for (int c = 0; c < 32; ++c) {
    uint2 diagn = diag;
    if (c + 1 < 32)
      diagn = *(const uint2*)&A[(size_t)((c + 1) * 64 + lane) * 64 + 2 * (c + 1)];

    for (int t = 0; t < prevcnt; t += 32) {
      unsigned r[32];
#pragma unroll
      for (int k = 0; k < 32; ++k) {
        int idx = prevbase + t + k;
        int lim = prevbase + prevcnt - 1;
        if (idx > lim) idx = lim;
        r[k] = A[(size_t)plist[idx] * 64 + lane];
      }
      unsigned acc = 0;
#pragma unroll
      for (int k = 0; k < 32; ++k) acc |= r[k];
      sup |= acc;
    }

    unsigned as0 = act & ~sup;
    unsigned lo = __builtin_amdgcn_readlane(as0, 2 * c);
    unsigned hi = __builtin_amdgcn_readlane(as0, 2 * c + 1);
    unsigned long long cand = ((unsigned long long)hi << 32) | lo;
    unsigned long long pickw = 0;
    unsigned mlo = diag.x, mhi = diag.y;
    int cbase = npick;
    while (cand) {
      int bpos = (int)__ffsll(cand) - 1;
      pickw |= 1ull << bpos;
      unsigned rlo = __builtin_amdgcn_readlane(mlo, bpos);
      unsigned rhi = __builtin_amdgcn_readlane(mhi, bpos);
      cand &= ~(((unsigned long long)rhi << 32) | rlo);
      if (lane == 0) plist[npick] = (unsigned short)(c * 64 + bpos);
      npick++;
    }
    if (lane == 2 * c)     mypm |= (unsigned)(pickw & 0xffffffffull);
    if (lane == 2 * c + 1) mypm |= (unsigned)(pickw >> 32);
    prevbase = cbase; prevcnt = npick - cbase;
    diag = diagn;
  }

  pm_s[lane] = mypm;
  fpr_s[lane] = INT_MAX;
  __syncthreads();

  int pre = 0;
  for (int w = 0; w < lane; ++w) pre += __popc(pm_s[w]);
  {
    unsigned w = mypm; int e = pre;
    while (w) {
      int bpos = __ffs(w) - 1; w &= w - 1;
      int rank = lane * 32 + bpos;
      ev_g[b * BN + e] = (unsigned short)rank;
      int g = (int)gtss[b * BN + rank];
      atomicMin(&fpr_s[g], rank);
      e++;
    }
  }
  __syncthreads();

  pm_g[b * 64 + lane] = mypm;
  fpr_g[b * 64 + lane] = fpr_s[lane];
  hp_g[b * 64 + lane] = 0u;
  if (lane == 0) {
    meta_g[b * 4 + 0] = npick;
    meta_g[b * 4 + 1] = 0;        // lastrem
    meta_g[b * 4 + 2] = npos;
  }
  for (int k = 0; k < 32; ++k) {
    int j = lane + k * 64;
    qs_g[b * BN + j] = 0.f;
    qc_g[b * BN + j] = 0;
  }
}

// ---------------------------- K3b: parallel per-box event contributions
__global__ __launch_bounds__(256) void k3b_events(
    const short* __restrict__ gtss, const float* __restrict__ pers,
    const unsigned* __restrict__ adj, const unsigned* __restrict__ pm_g,
    const int* __restrict__ fpr_g, int* __restrict__ meta_g,
    float* __restrict__ qs_g, int* __restrict__ qc_g, unsigned* __restrict__ hp_g)
{
  const int blk = blockIdx.x;       // 8 batches * 8 segments
  const int b = blk & 7;
  const int seg = blk >> 3;
  const int tid = threadIdx.x;
  __shared__ unsigned pm_s[64];
  __shared__ unsigned pre_s[64];
  __shared__ short gts_s[BN];       // 4 KB

  if (tid < 64) pm_s[tid] = pm_g[b * 64 + tid];
  for (int k = 0; k < 4; ++k)
    ((int*)gts_s)[tid + 256 * k] = ((const int*)(gtss + b * BN))[tid + 256 * k];
  __syncthreads();
  if (tid < 64) {
    int s = 0;
    for (int w = 0; w < tid; ++w) s += __popc(pm_s[w]);
    pre_s[tid] = (unsigned)s;
  }
  __syncthreads();

  const int j = seg * 256 + tid;
  const uint4* R = (const uint4*)(adj + ((size_t)b * BN + j) * 64);
  int frank = -1;
#pragma unroll
  for (int q = 0; q < 16; ++q) {
    uint4 r4 = R[q];
    unsigned m0 = r4.x & pm_s[q * 4 + 0];
    unsigned m1 = r4.y & pm_s[q * 4 + 1];
    unsigned m2 = r4.z & pm_s[q * 4 + 2];
    unsigned m3 = r4.w & pm_s[q * 4 + 3];
    if (frank < 0 && m0) frank = q * 128 +  0 + __ffs(m0) - 1;
    if (frank < 0 && m1) frank = q * 128 + 32 + __ffs(m1) - 1;
    if (frank < 0 && m2) frank = q * 128 + 64 + __ffs(m2) - 1;
    if (frank < 0 && m3) frank = q * 128 + 96 + __ffs(m3) - 1;
  }

  int gj = (int)gts_s[j];
  if (frank >= 0 && frank != j && gj >= 0) {
    int e = (int)pre_s[frank >> 5] + __popc(pm_s[frank >> 5] & ((1u << (frank & 31)) - 1u));
    int P = meta_g[b * 4 + 0];
    if (e == P - 1) atomicOr(&meta_g[b * 4 + 1], 1);
    int gt = (int)gts_s[frank];
    if (gj != gt) {
      atomicOr(&hp_g[b * 64 + (e >> 5)], 1u << (e & 31));
      if (fpr_g[b * 64 + gj] > frank) {
        atomicAdd(&qs_g[b * BN + e], pers[b * BN + j]);
        atomicAdd(&qc_g[b * BN + e], 1);
      }
    }
  }
}

// ---------------------------- K3c: event pass + final averaging (1 block)
__global__ __launch_bounds__(256) void k3c_loss(
    const float4* __restrict__ boxs, const float* __restrict__ scs,
    const short* __restrict__ gtss, const unsigned short* __restrict__ ev_g,
    const int* __restrict__ fpr_g, const int* __restrict__ meta_g,
    const float* __restrict__ qs_g, const int* __restrict__ qc_g,
    const unsigned* __restrict__ hp_g, float* __restrict__ out, int nb)
{
  const int tid = threadIdx.x;
  const int lane = tid & 63;
  const int wave = tid >> 6;
  __shared__ float redp[4][4];
  __shared__ float osum[2];
  if (tid == 0) { osum[0] = 0.f; osum[1] = 0.f; }

  for (int b = 0; b < nb; ++b) {
    const int P = meta_g[b * 4 + 0];
    const int lastrem = meta_g[b * 4 + 1];
    const int npos = meta_g[b * 4 + 2];
    float pull_l = 0.f, pcl = 0.f, push_l = 0.f, pshl = 0.f;
    for (int t = tid; t < P; t += 256) {
      int r = (int)ev_g[b * BN + t];
      int g = (int)gtss[b * BN + r];
      int fp = fpr_g[b * 64 + g];
      bool seen = (fp < r);
      bool hr = (t < P - 1) || (lastrem != 0);
      if (seen) {
        pcl += 1.f;
        if (hr) {
          float4 bA = boxs[b * BN + fp];
          float4 bB = boxs[b * BN + r];
          float io = iou_box(bA, bB);
          pull_l += -logf(1.f - THR + fmaxf(io, EPSF)) * scs[b * BN + r];
        }
      }
      if (hr && ((hp_g[b * 64 + (t >> 5)] >> (t & 31)) & 1u)) {
        pshl += 1.f;
        push_l += qs_g[b * BN + t] / ((float)qc_g[b * BN + t] + EPSF);
      }
    }
    for (int o = 1; o < 64; o <<= 1) {
      pull_l += __shfl_xor(pull_l, o);
      pcl    += __shfl_xor(pcl, o);
      push_l += __shfl_xor(push_l, o);
      pshl   += __shfl_xor(pshl, o);
    }
    if (lane == 0) { redp[wave][0] = pull_l; redp[wave][1] = pcl; redp[wave][2] = push_l; redp[wave][3] = pshl; }
    __syncthreads();
    if (tid == 0) {
      float Ps = 0.f, Pc = 0.f, Ss = 0.f, Sc = 0.f;
      for (int w = 0; w < 4; ++w) { Ps += redp[w][0]; Pc += redp[w][1]; Ss += redp[w][2]; Sc += redp[w][3]; }
      float gate = (npos > 1) ? 1.f : 0.f;
      osum[0] += gate * Ss / (Sc + EPSF);   // push
      osum[1] += gate * Ps / (Pc + EPSF);   // pull
    }
    __syncthreads();
  }
  if (tid == 0) {
    float inv = 1.f / (float)nb;
    out[0] = osum[0] * inv * PUSH_W;
    out[1] = osum[1] * inv * PULL_W;
  }
}

// =============================== fallback path (round-1 kernel, proven) =====
constexpr int NT = 256;
constexpr int PT = BN / NT;
constexpr int NW = NT / 64;

__global__ void nms_finalize_kernel(const float* __restrict__ bp, float* __restrict__ out, int nb) {
  if (threadIdx.x == 0 && blockIdx.x == 0) {
    float ps = 0.f, pl = 0.f;
    for (int b = 0; b < nb; ++b) { ps += bp[2 * b]; pl += bp[2 * b + 1]; }
    float inv = 1.f / (float)nb;
    out[0] = ps * inv * PUSH_W;
    out[1] = pl * inv * PULL_W;
  }
}

__global__ __launch_bounds__(NT) void nms_loss_kernel(
    const int* __restrict__ gti_all, const float* __restrict__ gtb_all,
    const float* __restrict__ prop_all, float* __restrict__ out_bp)
{
  const int b = blockIdx.x;
  const int tid = threadIdx.x;
  const int lane = tid & 63;
  const int wave = tid >> 6;

  __shared__ float4 box[BN];
  __shared__ float sc[BN];
  __shared__ float per[BN];
  __shared__ int gts[BN];
  __shared__ unsigned char act[BN];
  __shared__ int rec[BG];
  __shared__ float rs[NW];
  __shared__ int ri[NW];
  __shared__ int rrem[NW];
  __shared__ int rqc[NW];
  __shared__ float rqs[NW];
  __shared__ int rany[NW];
  __shared__ int sh_nact;
  __shared__ int sh_ig;
  __shared__ float4 sh_ibox;

  const int* gti = gti_all + b * BN;
  const float* GB = gtb_all + b * BG * 4;
  const float* P = prop_all + (size_t)b * BN * 5;

  int local_pos = 0;
  for (int k = 0; k < PT; ++k) {
    int j = tid + k * NT;
    float x1 = P[j * 5 + 0], y1 = P[j * 5 + 1];
    float x2 = P[j * 5 + 2], y2 = P[j * 5 + 3];
    float s = P[j * 5 + 4];
    box[j] = make_float4(x1, y1, x2, y2);
    sc[j] = s;
    int g = gti[j];
    gts[j] = g;
    unsigned char a = (g >= 0) ? 1 : 0;
    act[j] = a;
    local_pos += a;
    float pv = 0.f;
    if (g >= 0) {
      float4 gb = make_float4(GB[g * 4], GB[g * 4 + 1], GB[g * 4 + 2], GB[g * 4 + 3]);
      float i2 = iou_box(gb, make_float4(x1, y1, x2, y2));
      pv = -logf(EPSF + i2) * s;
    }
    per[j] = pv;
  }
  if (tid < BG) rec[tid] = -1;
  for (int off = 32; off; off >>= 1) local_pos += __shfl_down(local_pos, off);
  if (lane == 0) rrem[wave] = local_pos;
  __syncthreads();
  int n_pos = 0;
  if (tid == 0) {
    for (int w = 0; w < NW; ++w) n_pos += rrem[w];
    sh_nact = n_pos;
  }
  float pull_sum = 0.f, push_sum = 0.f, pull_cnt = 0.f, push_cnt = 0.f;
  int t0_hasrem = 0;
  __syncthreads();

  while (true) {
    int nact = sh_nact;
    if (nact <= 0) break;
    float bs = -INFINITY;
    int bi = BN;
    for (int k = 0; k < PT; ++k) {
      int j = tid + k * NT;
      if (act[j]) {
        float s = sc[j];
        if (s > bs || (s == bs && j < bi)) { bs = s; bi = j; }
      }
    }
    for (int off = 32; off; off >>= 1) {
      float os = __shfl_down(bs, off);
      int oi = __shfl_down(bi, off);
      if (os > bs || (os == bs && oi < bi)) { bs = os; bi = oi; }
    }
    if (lane == 0) { rs[wave] = bs; ri[wave] = bi; }
    __syncthreads();
    if (tid == 0) {
      float cs = rs[0]; int ci = ri[0];
      for (int w = 1; w < NW; ++w)
        if (rs[w] > cs || (rs[w] == cs && ri[w] < ci)) { cs = rs[w]; ci = ri[w]; }
      int i = ci;
      int ig = gts[i];
      act[i] = 0;
      t0_hasrem = (nact - 1 > 0);
      int r = rec[ig];
      if (r >= 0) {
        pull_cnt += 1.f;
        if (t0_hasrem) {
          float i2 = iou_box(box[r], box[i]);
          float m = fmaxf(i2, EPSF);
          pull_sum += -logf(1.f - THR + m) * sc[i];
        }
      } else {
        rec[ig] = i;
      }
      sh_ig = ig; sh_ibox = box[i];
    }
    __syncthreads();
    float4 ib = sh_ibox;
    int igx = sh_ig;
    int removed = 0, qcc = 0, anyp = 0;
    float qss = 0.f;
    for (int k = 0; k < PT; ++k) {
      int j = tid + k * NT;
      if (act[j]) {
        float i2 = iou_box(ib, box[j]);
        if (i2 > THR) {
          act[j] = 0;
          removed++;
          int gj = gts[j];
          if (gj != igx) {
            anyp = 1;
            if (rec[gj] < 0) { qcc++; qss += per[j]; }
          }
        }
      }
    }
    for (int off = 32; off; off >>= 1) {
      removed += __shfl_down(removed, off);
      qcc += __shfl_down(qcc, off);
      qss += __shfl_down(qss, off);
      anyp |= __shfl_down(anyp, off);
    }
    if (lane == 0) { rrem[wave] = removed; rqc[wave] = qcc; rqs[wave] = qss; rany[wave] = anyp; }
    __syncthreads();
    if (tid == 0) {
      int rm = 0, qct = 0, ap = 0; float qst = 0.f;
      for (int w = 0; w < NW; ++w) { rm += rrem[w]; qct += rqc[w]; qst += rqs[w]; ap |= rany[w]; }
      sh_nact = nact - 1 - rm;
      if (t0_hasrem && ap) {
        push_sum += qst / ((float)qct + EPSF);
        push_cnt += 1.f;
      }
    }
    __syncthreads();
  }

  if (tid == 0) {
    float gate = (n_pos > 1) ? 1.f : 0.f;
    out_bp[b * 2 + 0] = gate * push_sum / (push_cnt + EPSF);
    out_bp[b * 2 + 1] = gate * pull_sum / (pull_cnt + EPSF);
  }
}

// ============================================================== launch =====
extern "C" void kernel_launch(void* const* d_in, const int* in_sizes, int n_in,
                              void* d_out, int out_size, void* d_ws, size_t ws_size,
                              hipStream_t stream) {
  const int* gti = (const int*)d_in[1];
  const float* gtb = (const float*)d_in[2];
  const float* props = (const float*)d_in[3];
  float* out = (float*)d_out;
  const int nb = in_sizes[1] / BN;   // 8

  // ws layout (bytes)
  const size_t off_adj  = 0;                                    // nb*BN*64*4
  const size_t off_box  = off_adj  + (size_t)nb * BN * 64 * 4;  // nb*BN*16
  const size_t off_per  = off_box  + (size_t)nb * BN * 16;      // nb*BN*4
  const size_t off_sc   = off_per  + (size_t)nb * BN * 4;       // nb*BN*4
  const size_t off_qs   = off_sc   + (size_t)nb * BN * 4;       // nb*BN*4
  const size_t off_qc   = off_qs   + (size_t)nb * BN * 4;       // nb*BN*4
  const size_t off_gts  = off_qc   + (size_t)nb * BN * 4;       // nb*BN*2
  const size_t off_ev   = off_gts  + (size_t)nb * BN * 2;       // nb*BN*2
  const size_t off_pm   = off_ev   + (size_t)nb * BN * 2;       // nb*64*4
  const size_t off_fpr  = off_pm   + (size_t)nb * 64 * 4;       // nb*64*4
  const size_t off_hp   = off_fpr  + (size_t)nb * 64 * 4;       // nb*64*4
  const size_t off_meta = off_hp   + (size_t)nb * 64 * 4;       // nb*4*4
  const size_t needed   = off_meta + (size_t)nb * 4 * 4;

  if (ws_size >= needed && nb == 8) {
    char* ws = (char*)d_ws;
    unsigned* adj = (unsigned*)(ws + off_adj);
    float4* boxs = (float4*)(ws + off_box);
    float* pers = (float*)(ws + off_per);
    float* scs = (float*)(ws + off_sc);
    float* qs = (float*)(ws + off_qs);
    int* qc = (int*)(ws + off_qc);
    short* gtss = (short*)(ws + off_gts);
    unsigned short* ev = (unsigned short*)(ws + off_ev);
    unsigned* pm = (unsigned*)(ws + off_pm);
    int* fpr = (int*)(ws + off_fpr);
    unsigned* hp = (unsigned*)(ws + off_hp);
    int* meta = (int*)(ws + off_meta);

    k1_sort<<<nb * 8, 256, 0, stream>>>(gti, gtb, props, boxs, pers, gtss, scs);
    k2_adj<<<nb * 32, 512, 0, stream>>>(boxs, adj);
    k3a_resolve<<<nb, 64, 0, stream>>>(gtss, adj, pm, fpr, ev, meta, qs, qc, hp);
    k3b_events<<<nb * 8, 256, 0, stream>>>(gtss, pers, adj, pm, fpr, meta, qs, qc, hp);
    k3c_loss<<<1, 256, 0, stream>>>(boxs, scs, gtss, ev, fpr, meta, qs, qc, hp, out, nb);
  } else {
    float* bp = (float*)d_ws;
    nms_loss_kernel<<<nb, NT, 0, stream>>>(gti, gtb, props, bp);
    nms_finalize_kernel<<<1, 64, 0, stream>>>(bp, out, nb);
  }
}

// Round 7
// 120.258 us; speedup vs baseline: 1.1118x; 1.0802x over previous
//
#include <hip/hip_runtime.h>
#include <math.h>
#include <limits.h>

#define EPSF 1e-6f
#define THR 0.5f
#define PUSH_W 1.0f
#define PULL_W 1.0f

constexpr int BN = 2048;    // proposals per batch
constexpr int BG = 64;      // gt boxes per batch

__device__ __forceinline__ float iou_box(float4 a, float4 b) {
  float aa = (a.z - a.x) * (a.w - a.y);
  float ab = (b.z - b.x) * (b.w - b.y);
  float w = fmaxf(fminf(a.z, b.z) - fmaxf(a.x, b.x), 0.f);
  float h = fmaxf(fminf(a.w, b.w) - fmaxf(a.y, b.y), 0.f);
  float inter = w * h;
  return inter / (aa + ab - inter + EPSF);
}

// -------------------------------------------------- K1: rank-by-count sort
__global__ __launch_bounds__(256) void k1_sort(
    const int* __restrict__ gti_all, const float* __restrict__ gtb_all,
    const float* __restrict__ prop_all,
    float4* __restrict__ boxs, float* __restrict__ pers,
    short* __restrict__ gtss, float* __restrict__ scs)
{
  const int b = blockIdx.x & 7;        // batch
  const int rg = blockIdx.x >> 3;      // row group
  const int tid = threadIdx.x;
  __shared__ unsigned long long key[BN];   // 16 KB

  const float* P = prop_all + (size_t)b * BN * 5;
  const int* gti = gti_all + b * BN;
  const float* GB = gtb_all + b * BG * 4;

  for (int k = 0; k < 8; ++k) {
    int j = tid + k * 256;
    unsigned bits = __float_as_uint(P[j * 5 + 4]);
    key[j] = ((unsigned long long)bits << 32) | (unsigned)(BN - 1 - j);
  }
  __syncthreads();

  const int r = rg * 256 + tid;
  const unsigned long long myk = key[r];
  int rank = 0;
  const ulonglong2* K2 = (const ulonglong2*)key;
#pragma unroll 8
  for (int j = 0; j < BN / 2; ++j) {
    ulonglong2 kk = K2[j];
    rank += (kk.x > myk) ? 1 : 0;
    rank += (kk.y > myk) ? 1 : 0;
  }

  int idx = (BN - 1) - (int)(myk & 0xffffffffu);
  float x1 = P[idx * 5 + 0], y1 = P[idx * 5 + 1];
  float x2 = P[idx * 5 + 2], y2 = P[idx * 5 + 3];
  float s = __uint_as_float((unsigned)(myk >> 32));
  int g = gti[idx];
  float4 bx = make_float4(x1, y1, x2, y2);
  boxs[b * BN + rank] = bx;
  scs[b * BN + rank] = s;
  gtss[b * BN + rank] = (short)g;
  float pv = 0.f;
  if (g >= 0) {
    float4 gb = make_float4(GB[g * 4 + 0], GB[g * 4 + 1], GB[g * 4 + 2], GB[g * 4 + 3]);
    float i2 = iou_box(gb, bx);
    pv = -logf(EPSF + i2) * s;
  }
  pers[b * BN + rank] = pv;
}

// ------------------------------------------------------------- K2: adjacency
// chunk-major output: adjC[(b*32+c)*2048 + j] = uint2{cols c*64..+31, +32..+63} of row j.
__global__ __launch_bounds__(512) void k2_adj(
    const float4* __restrict__ boxs, uint2* __restrict__ adjC)
{
  const int b = blockIdx.x & 7;
  const int rg = blockIdx.x >> 3;      // 0..31
  const int tid = threadIdx.x;         // 0..511
  const int lane = tid & 63;
  const int w = tid >> 6;              // wave 0..7 -> cols w*256..+256
  __shared__ float4 bs[BN];            // 32 KB

  const float4* B = boxs + b * BN;
  for (int k = tid; k < BN; k += 512) bs[k] = B[k];
  __syncthreads();

  const int row = rg * 64 + lane;
  const float4 rb = bs[row];
  const float aa = (rb.z - rb.x) * (rb.w - rb.y);

  unsigned out[8];
#pragma unroll
  for (int ww = 0; ww < 8; ++ww) {
    unsigned bits = 0;
    const int j0 = w * 256 + ww * 32;
#pragma unroll
    for (int jj = 0; jj < 32; ++jj) {
      float4 bj = bs[j0 + jj];                 // broadcast read
      float wd = fmaxf(fminf(rb.z, bj.z) - fmaxf(rb.x, bj.x), 0.f);
      float ht = fmaxf(fminf(rb.w, bj.w) - fmaxf(rb.y, bj.y), 0.f);
      float inter = wd * ht;
      if (inter > 0.f) {                       // exec-mask skip of IEEE div
        float ab = (bj.z - bj.x) * (bj.w - bj.y);
        float iou = inter / (aa + ab - inter + EPSF);
        bits |= (iou > THR) ? (1u << jj) : 0u;
      }
    }
    out[ww] = bits;
  }
  uint2* CO = adjC + (size_t)b * 32 * 2048;
#pragma unroll
  for (int k = 0; k < 4; ++k) {
    int c = w * 4 + k;
    CO[(size_t)c * 2048 + row] = make_uint2(out[2 * k], out[2 * k + 1]);
  }
}

// ------------------------- K3a: streaming-sup greedy resolve (1 wave/batch)
// lane owns ranks {k*64+lane}: act/sup bit k. Per chunk: in-chunk greedy on
// diagonal slice, then sup-update all ranks from the prefetched column block.
// No pick-dependent global loads -> latency fully hidden by double buffer.
__global__ __launch_bounds__(64) void k3a_resolve(
    const short* __restrict__ gtss, const uint2* __restrict__ adjC,
    unsigned* __restrict__ pm_g, int* __restrict__ fpr_g,
    unsigned short* __restrict__ ev_g, int* __restrict__ meta_g,
    float* __restrict__ qs_g, int* __restrict__ qc_g, unsigned* __restrict__ hp_g)
{
  const int b = blockIdx.x;
  const int lane = threadIdx.x;       // 0..63
  __shared__ unsigned pm_lds[64];
  __shared__ int fpr_s[64];

  const uint2* Cb = adjC + (size_t)b * 32 * 2048;

  // act word: bit k = rank k*64+lane is positive
  unsigned act = 0;
#pragma unroll
  for (int k = 0; k < 32; ++k)
    if (gtss[b * BN + k * 64 + lane] >= 0) act |= (1u << k);
  int npos = __popc(act);
  for (int o = 1; o < 64; o <<= 1) npos += __shfl_xor(npos, o);

  unsigned sup = 0;
  int npick = 0;                      // wave-uniform

  uint2 bufA[32], bufB[32];
#pragma unroll
  for (int k = 0; k < 32; ++k) bufA[k] = Cb[(size_t)0 * 2048 + k * 64 + lane];
#pragma unroll
  for (int k = 0; k < 32; ++k) bufB[k] = Cb[(size_t)1 * 2048 + k * 64 + lane];

#define CHUNK(cc, BUF)                                                         \
  {                                                                            \
    unsigned mybit = ((act >> (cc)) & ~(sup >> (cc))) & 1u;                    \
    unsigned long long row64 =                                                 \
        ((unsigned long long)BUF[cc].y << 32) | (unsigned long long)BUF[cc].x; \
    unsigned long long pickw = 0ull;                                           \
    unsigned long long bal = __ballot(mybit != 0u);                            \
    while (bal) {                                                              \
      int bpos = (int)__ffsll(bal) - 1;                                        \
      pickw |= 1ull << bpos;                                                   \
      mybit &= ~(unsigned)((row64 >> bpos) & 1ull);                            \
      bal = __ballot(mybit != 0u);                                             \
    }                                                                          \
    if (pickw != 0ull) {                                                       \
      npick += (int)__popcll(pickw);                                           \
      unsigned pwlo = (unsigned)pickw;                                         \
      unsigned pwhi = (unsigned)(pickw >> 32);                                 \
      if (lane == 0) { pm_lds[2*(cc)] = pwlo; pm_lds[2*(cc)+1] = pwhi; }       \
      _Pragma("unroll")                                                        \
      for (int k = 0; k < 32; ++k) {                                           \
        unsigned hit = (BUF[k].x & pwlo) | (BUF[k].y & pwhi);                  \
        sup |= (hit != 0u) ? (1u << k) : 0u;                                   \
      }                                                                        \
    } else if (lane == 0) {                                                    \
      pm_lds[2*(cc)] = 0u; pm_lds[2*(cc)+1] = 0u;                              \
    }                                                                          \
    if ((cc) + 2 < 32) {                                                       \
      _Pragma("unroll")                                                        \
      for (int k = 0; k < 32; ++k)                                             \
        BUF[k] = Cb[(size_t)((cc) + 2) * 2048 + k * 64 + lane];                \
    }                                                                          \
  }

  CHUNK(0, bufA)  CHUNK(1, bufB)  CHUNK(2, bufA)  CHUNK(3, bufB)
  CHUNK(4, bufA)  CHUNK(5, bufB)  CHUNK(6, bufA)  CHUNK(7, bufB)
  CHUNK(8, bufA)  CHUNK(9, bufB)  CHUNK(10, bufA) CHUNK(11, bufB)
  CHUNK(12, bufA) CHUNK(13, bufB) CHUNK(14, bufA) CHUNK(15, bufB)
  CHUNK(16, bufA) CHUNK(17, bufB) CHUNK(18, bufA) CHUNK(19, bufB)
  CHUNK(20, bufA) CHUNK(21, bufB) CHUNK(22, bufA) CHUNK(23, bufB)
  CHUNK(24, bufA) CHUNK(25, bufB) CHUNK(26, bufA) CHUNK(27, bufB)
  CHUNK(28, bufA) CHUNK(29, bufB) CHUNK(30, bufA) CHUNK(31, bufB)
#undef CHUNK

  fpr_s[lane] = INT_MAX;
  __syncthreads();

  // epilogue: prefix popcounts, ev2rank, fpr
  unsigned mypm = pm_lds[lane];       // word covers ranks lane*32..+31
  int pre = 0;
  for (int w = 0; w < lane; ++w) pre += __popc(pm_lds[w]);
  {
    unsigned w = mypm; int e = pre;
    while (w) {
      int bpos = __ffs(w) - 1; w &= w - 1;
      int rank = lane * 32 + bpos;
      ev_g[b * BN + e] = (unsigned short)rank;
      int g = (int)gtss[b * BN + rank];
      atomicMin(&fpr_s[g], rank);
      e++;
    }
  }
  __syncthreads();

  pm_g[b * 64 + lane] = mypm;
  fpr_g[b * 64 + lane] = fpr_s[lane];
  hp_g[b * 64 + lane] = 0u;
  if (lane == 0) {
    meta_g[b * 4 + 0] = npick;
    meta_g[b * 4 + 1] = 0;        // lastrem
    meta_g[b * 4 + 2] = npos;
  }
  for (int k = 0; k < 32; ++k) {
    int j = lane + k * 64;
    qs_g[b * BN + j] = 0.f;
    qc_g[b * BN + j] = 0;
  }
}

// ---------------------------- K3b: parallel per-box event contributions
__global__ __launch_bounds__(256) void k3b_events(
    const short* __restrict__ gtss, const float* __restrict__ pers,
    const uint2* __restrict__ adjC, const unsigned* __restrict__ pm_g,
    const int* __restrict__ fpr_g, int* __restrict__ meta_g,
    float* __restrict__ qs_g, int* __restrict__ qc_g, unsigned* __restrict__ hp_g)
{
  const int blk = blockIdx.x;       // 8 batches * 8 segments
  const int b = blk & 7;
  const int seg = blk >> 3;
  const int tid = threadIdx.x;
  __shared__ unsigned pm_s[64];
  __shared__ unsigned pre_s[64];
  __shared__ short gts_s[BN];       // 4 KB

  if (tid < 64) pm_s[tid] = pm_g[b * 64 + tid];
  for (int k = 0; k < 4; ++k)
    ((int*)gts_s)[tid + 256 * k] = ((const int*)(gtss + b * BN))[tid + 256 * k];
  __syncthreads();
  if (tid < 64) {
    int s = 0;
    for (int w = 0; w < tid; ++w) s += __popc(pm_s[w]);
    pre_s[tid] = (unsigned)s;
  }
  __syncthreads();

  const int j = seg * 256 + tid;
  const uint2* Cj = adjC + (size_t)b * 32 * 2048 + j;
  int frank = -1;
#pragma unroll
  for (int c = 0; c < 32; ++c) {
    uint2 v = Cj[(size_t)c * 2048];
    unsigned m0 = v.x & pm_s[2 * c];
    unsigned m1 = v.y & pm_s[2 * c + 1];
    if (frank < 0 && m0) frank = c * 64 + __ffs(m0) - 1;
    if (frank < 0 && m1) frank = c * 64 + 32 + __ffs(m1) - 1;
  }

  int gj = (int)gts_s[j];
  if (frank >= 0 && frank != j && gj >= 0) {
    int e = (int)pre_s[frank >> 5] + __popc(pm_s[frank >> 5] & ((1u << (frank & 31)) - 1u));
    int P = meta_g[b * 4 + 0];
    if (e == P - 1) atomicOr(&meta_g[b * 4 + 1], 1);
    int gt = (int)gts_s[frank];
    if (gj != gt) {
      atomicOr(&hp_g[b * 64 + (e >> 5)], 1u << (e & 31));
      if (fpr_g[b * 64 + gj] > frank) {
        atomicAdd(&qs_g[b * BN + e], pers[b * BN + j]);
        atomicAdd(&qc_g[b * BN + e], 1);
      }
    }
  }
}

// ---------------------------- K3c: event pass + final averaging (1 block)
__global__ __launch_bounds__(256) void k3c_loss(
    const float4* __restrict__ boxs, const float* __restrict__ scs,
    const short* __restrict__ gtss, const unsigned short* __restrict__ ev_g,
    const int* __restrict__ fpr_g, const int* __restrict__ meta_g,
    const float* __restrict__ qs_g, const int* __restrict__ qc_g,
    const unsigned* __restrict__ hp_g, float* __restrict__ out, int nb)
{
  const int tid = threadIdx.x;
  const int lane = tid & 63;
  const int wave = tid >> 6;
  __shared__ float redp[4][4];
  __shared__ float osum[2];
  if (tid == 0) { osum[0] = 0.f; osum[1] = 0.f; }

  for (int b = 0; b < nb; ++b) {
    const int P = meta_g[b * 4 + 0];
    const int lastrem = meta_g[b * 4 + 1];
    const int npos = meta_g[b * 4 + 2];
    float pull_l = 0.f, pcl = 0.f, push_l = 0.f, pshl = 0.f;
    for (int t = tid; t < P; t += 256) {
      int r = (int)ev_g[b * BN + t];
      int g = (int)gtss[b * BN + r];
      int fp = fpr_g[b * 64 + g];
      bool seen = (fp < r);
      bool hr = (t < P - 1) || (lastrem != 0);
      if (seen) {
        pcl += 1.f;
        if (hr) {
          float4 bA = boxs[b * BN + fp];
          float4 bB = boxs[b * BN + r];
          float io = iou_box(bA, bB);
          pull_l += -logf(1.f - THR + fmaxf(io, EPSF)) * scs[b * BN + r];
        }
      }
      if (hr && ((hp_g[b * 64 + (t >> 5)] >> (t & 31)) & 1u)) {
        pshl += 1.f;
        push_l += qs_g[b * BN + t] / ((float)qc_g[b * BN + t] + EPSF);
      }
    }
    for (int o = 1; o < 64; o <<= 1) {
      pull_l += __shfl_xor(pull_l, o);
      pcl    += __shfl_xor(pcl, o);
      push_l += __shfl_xor(push_l, o);
      pshl   += __shfl_xor(pshl, o);
    }
    if (lane == 0) { redp[wave][0] = pull_l; redp[wave][1] = pcl; redp[wave][2] = push_l; redp[wave][3] = pshl; }
    __syncthreads();
    if (tid == 0) {
      float Ps = 0.f, Pc = 0.f, Ss = 0.f, Sc = 0.f;
      for (int w = 0; w < 4; ++w) { Ps += redp[w][0]; Pc += redp[w][1]; Ss += redp[w][2]; Sc += redp[w][3]; }
      float gate = (npos > 1) ? 1.f : 0.f;
      osum[0] += gate * Ss / (Sc + EPSF);   // push
      osum[1] += gate * Ps / (Pc + EPSF);   // pull
    }
    __syncthreads();
  }
  if (tid == 0) {
    float inv = 1.f / (float)nb;
    out[0] = osum[0] * inv * PUSH_W;
    out[1] = osum[1] * inv * PULL_W;
  }
}

// =============================== fallback path (round-1 kernel, proven) =====
constexpr int NT = 256;
constexpr int PT = BN / NT;
constexpr int NW = NT / 64;

__global__ void nms_finalize_kernel(const float* __restrict__ bp, float* __restrict__ out, int nb) {
  if (threadIdx.x == 0 && blockIdx.x == 0) {
    float ps = 0.f, pl = 0.f;
    for (int b = 0; b < nb; ++b) { ps += bp[2 * b]; pl += bp[2 * b + 1]; }
    float inv = 1.f / (float)nb;
    out[0] = ps * inv * PUSH_W;
    out[1] = pl * inv * PULL_W;
  }
}

__global__ __launch_bounds__(NT) void nms_loss_kernel(
    const int* __restrict__ gti_all, const float* __restrict__ gtb_all,
    const float* __restrict__ prop_all, float* __restrict__ out_bp)
{
  const int b = blockIdx.x;
  const int tid = threadIdx.x;
  const int lane = tid & 63;
  const int wave = tid >> 6;

  __shared__ float4 box[BN];
  __shared__ float sc[BN];
  __shared__ float per[BN];
  __shared__ int gts[BN];
  __shared__ unsigned char act[BN];
  __shared__ int rec[BG];
  __shared__ float rs[NW];
  __shared__ int ri[NW];
  __shared__ int rrem[NW];
  __shared__ int rqc[NW];
  __shared__ float rqs[NW];
  __shared__ int rany[NW];
  __shared__ int sh_nact;
  __shared__ int sh_ig;
  __shared__ float4 sh_ibox;

  const int* gti = gti_all + b * BN;
  const float* GB = gtb_all + b * BG * 4;
  const float* P = prop_all + (size_t)b * BN * 5;

  int local_pos = 0;
  for (int k = 0; k < PT; ++k) {
    int j = tid + k * NT;
    float x1 = P[j * 5 + 0], y1 = P[j * 5 + 1];
    float x2 = P[j * 5 + 2], y2 = P[j * 5 + 3];
    float s = P[j * 5 + 4];
    box[j] = make_float4(x1, y1, x2, y2);
    sc[j] = s;
    int g = gti[j];
    gts[j] = g;
    unsigned char a = (g >= 0) ? 1 : 0;
    act[j] = a;
    local_pos += a;
    float pv = 0.f;
    if (g >= 0) {
      float4 gb = make_float4(GB[g * 4], GB[g * 4 + 1], GB[g * 4 + 2], GB[g * 4 + 3]);
      float i2 = iou_box(gb, make_float4(x1, y1, x2, y2));
      pv = -logf(EPSF + i2) * s;
    }
    per[j] = pv;
  }
  if (tid < BG) rec[tid] = -1;
  for (int off = 32; off; off >>= 1) local_pos += __shfl_down(local_pos, off);
  if (lane == 0) rrem[wave] = local_pos;
  __syncthreads();
  int n_pos = 0;
  if (tid == 0) {
    for (int w = 0; w < NW; ++w) n_pos += rrem[w];
    sh_nact = n_pos;
  }
  float pull_sum = 0.f, push_sum = 0.f, pull_cnt = 0.f, push_cnt = 0.f;
  int t0_hasrem = 0;
  __syncthreads();

  while (true) {
    int nact = sh_nact;
    if (nact <= 0) break;
    float bs = -INFINITY;
    int bi = BN;
    for (int k = 0; k < PT; ++k) {
      int j = tid + k * NT;
      if (act[j]) {
        float s = sc[j];
        if (s > bs || (s == bs && j < bi)) { bs = s; bi = j; }
      }
    }
    for (int off = 32; off; off >>= 1) {
      float os = __shfl_down(bs, off);
      int oi = __shfl_down(bi, off);
      if (os > bs || (os == bs && oi < bi)) { bs = os; bi = oi; }
    }
    if (lane == 0) { rs[wave] = bs; ri[wave] = bi; }
    __syncthreads();
    if (tid == 0) {
      float cs = rs[0]; int ci = ri[0];
      for (int w = 1; w < NW; ++w)
        if (rs[w] > cs || (rs[w] == cs && ri[w] < ci)) { cs = rs[w]; ci = ri[w]; }
      int i = ci;
      int ig = gts[i];
      act[i] = 0;
      t0_hasrem = (nact - 1 > 0);
      int r = rec[ig];
      if (r >= 0) {
        pull_cnt += 1.f;
        if (t0_hasrem) {
          float i2 = iou_box(box[r], box[i]);
          float m = fmaxf(i2, EPSF);
          pull_sum += -logf(1.f - THR + m) * sc[i];
        }
      } else {
        rec[ig] = i;
      }
      sh_ig = ig; sh_ibox = box[i];
    }
    __syncthreads();
    float4 ib = sh_ibox;
    int igx = sh_ig;
    int removed = 0, qcc = 0, anyp = 0;
    float qss = 0.f;
    for (int k = 0; k < PT; ++k) {
      int j = tid + k * NT;
      if (act[j]) {
        float i2 = iou_box(ib, box[j]);
        if (i2 > THR) {
          act[j] = 0;
          removed++;
          int gj = gts[j];
          if (gj != igx) {
            anyp = 1;
            if (rec[gj] < 0) { qcc++; qss += per[j]; }
          }
        }
      }
    }
    for (int off = 32; off; off >>= 1) {
      removed += __shfl_down(removed, off);
      qcc += __shfl_down(qcc, off);
      qss += __shfl_down(qss, off);
      anyp |= __shfl_down(anyp, off);
    }
    if (lane == 0) { rrem[wave] = removed; rqc[wave] = qcc; rqs[wave] = qss; rany[wave] = anyp; }
    __syncthreads();
    if (tid == 0) {
      int rm = 0, qct = 0, ap = 0; float qst = 0.f;
      for (int w = 0; w < NW; ++w) { rm += rrem[w]; qct += rqc[w]; qst += rqs[w]; ap |= rany[w]; }
      sh_nact = nact - 1 - rm;
      if (t0_hasrem && ap) {
        push_sum += qst / ((float)qct + EPSF);
        push_cnt += 1.f;
      }
    }
    __syncthreads();
  }

  if (tid == 0) {
    float gate = (n_pos > 1) ? 1.f : 0.f;
    out_bp[b * 2 + 0] = gate * push_sum / (push_cnt + EPSF);
    out_bp[b * 2 + 1] = gate * pull_sum / (pull_cnt + EPSF);
  }
}

// ============================================================== launch =====
extern "C" void kernel_launch(void* const* d_in, const int* in_sizes, int n_in,
                              void* d_out, int out_size, void* d_ws, size_t ws_size,
                              hipStream_t stream) {
  const int* gti = (const int*)d_in[1];
  const float* gtb = (const float*)d_in[2];
  const float* props = (const float*)d_in[3];
  float* out = (float*)d_out;
  const int nb = in_sizes[1] / BN;   // 8

  // ws layout (bytes)
  const size_t off_adj  = 0;                                    // nb*32*2048*8
  const size_t off_box  = off_adj  + (size_t)nb * BN * 64 * 4;  // nb*BN*16
  const size_t off_per  = off_box  + (size_t)nb * BN * 16;      // nb*BN*4
  const size_t off_sc   = off_per  + (size_t)nb * BN * 4;       // nb*BN*4
  const size_t off_qs   = off_sc   + (size_t)nb * BN * 4;       // nb*BN*4
  const size_t off_qc   = off_qs   + (size_t)nb * BN * 4;       // nb*BN*4
  const size_t off_gts  = off_qc   + (size_t)nb * BN * 4;       // nb*BN*2
  const size_t off_ev   = off_gts  + (size_t)nb * BN * 2;       // nb*BN*2
  const size_t off_pm   = off_ev   + (size_t)nb * BN * 2;       // nb*64*4
  const size_t off_fpr  = off_pm   + (size_t)nb * 64 * 4;       // nb*64*4
  const size_t off_hp   = off_fpr  + (size_t)nb * 64 * 4;       // nb*64*4
  const size_t off_meta = off_hp   + (size_t)nb * 64 * 4;       // nb*4*4
  const size_t needed   = off_meta + (size_t)nb * 4 * 4;

  if (ws_size >= needed && nb == 8) {
    char* ws = (char*)d_ws;
    uint2* adjC = (uint2*)(ws + off_adj);
    float4* boxs = (float4*)(ws + off_box);
    float* pers = (float*)(ws + off_per);
    float* scs = (float*)(ws + off_sc);
    float* qs = (float*)(ws + off_qs);
    int* qc = (int*)(ws + off_qc);
    short* gtss = (short*)(ws + off_gts);
    unsigned short* ev = (unsigned short*)(ws + off_ev);
    unsigned* pm = (unsigned*)(ws + off_pm);
    int* fpr = (int*)(ws + off_fpr);
    unsigned* hp = (unsigned*)(ws + off_hp);
    int* meta = (int*)(ws + off_meta);

    k1_sort<<<nb * 8, 256, 0, stream>>>(gti, gtb, props, boxs, pers, gtss, scs);
    k2_adj<<<nb * 32, 512, 0, stream>>>(boxs, adjC);
    k3a_resolve<<<nb, 64, 0, stream>>>(gtss, adjC, pm, fpr, ev, meta, qs, qc, hp);
    k3b_events<<<nb * 8, 256, 0, stream>>>(gtss, pers, adjC, pm, fpr, meta, qs, qc, hp);
    k3c_loss<<<1, 256, 0, stream>>>(boxs, scs, gtss, ev, fpr, meta, qs, qc, hp, out, nb);
  } else {
    float* bp = (float*)d_ws;
    nms_loss_kernel<<<nb, NT, 0, stream>>>(gti, gtb, props, bp);
    nms_finalize_kernel<<<1, 64, 0, stream>>>(bp, out, nb);
  }
}

// Round 8
// 117.254 us; speedup vs baseline: 1.1402x; 1.0256x over previous
//
#include <hip/hip_runtime.h>
#include <math.h>
#include <limits.h>

#define EPSF 1e-6f
#define THR 0.5f
#define PUSH_W 1.0f
#define PULL_W 1.0f

constexpr int BN = 2048;    // proposals per batch
constexpr int BG = 64;      // gt boxes per batch

__device__ __forceinline__ float iou_box(float4 a, float4 b) {
  float aa = (a.z - a.x) * (a.w - a.y);
  float ab = (b.z - b.x) * (b.w - b.y);
  float w = fmaxf(fminf(a.z, b.z) - fmaxf(a.x, b.x), 0.f);
  float h = fmaxf(fminf(a.w, b.w) - fmaxf(a.y, b.y), 0.f);
  float inter = w * h;
  return inter / (aa + ab - inter + EPSF);
}

// -------------------------------------------------- K1: rank-by-count sort
__global__ __launch_bounds__(256) void k1_sort(
    const int* __restrict__ gti_all, const float* __restrict__ gtb_all,
    const float* __restrict__ prop_all,
    float4* __restrict__ boxs, float* __restrict__ pers,
    short* __restrict__ gtss, float* __restrict__ scs)
{
  const int b = blockIdx.x & 7;        // batch
  const int rg = blockIdx.x >> 3;      // row group
  const int tid = threadIdx.x;
  __shared__ unsigned long long key[BN];   // 16 KB

  const float* P = prop_all + (size_t)b * BN * 5;
  const int* gti = gti_all + b * BN;
  const float* GB = gtb_all + b * BG * 4;

  for (int k = 0; k < 8; ++k) {
    int j = tid + k * 256;
    unsigned bits = __float_as_uint(P[j * 5 + 4]);
    key[j] = ((unsigned long long)bits << 32) | (unsigned)(BN - 1 - j);
  }
  __syncthreads();

  const int r = rg * 256 + tid;
  const unsigned long long myk = key[r];
  int rank = 0;
  const ulonglong2* K2 = (const ulonglong2*)key;
#pragma unroll 8
  for (int j = 0; j < BN / 2; ++j) {
    ulonglong2 kk = K2[j];
    rank += (kk.x > myk) ? 1 : 0;
    rank += (kk.y > myk) ? 1 : 0;
  }

  int idx = (BN - 1) - (int)(myk & 0xffffffffu);
  float x1 = P[idx * 5 + 0], y1 = P[idx * 5 + 1];
  float x2 = P[idx * 5 + 2], y2 = P[idx * 5 + 3];
  float s = __uint_as_float((unsigned)(myk >> 32));
  int g = gti[idx];
  float4 bx = make_float4(x1, y1, x2, y2);
  boxs[b * BN + rank] = bx;
  scs[b * BN + rank] = s;
  gtss[b * BN + rank] = (short)g;
  float pv = 0.f;
  if (g >= 0) {
    float4 gb = make_float4(GB[g * 4 + 0], GB[g * 4 + 1], GB[g * 4 + 2], GB[g * 4 + 3]);
    float i2 = iou_box(gb, bx);
    pv = -logf(EPSF + i2) * s;
  }
  pers[b * BN + rank] = pv;
}

// ------------------------------------------------------------- K2: adjacency
// Branchless, division-free predicate: iou>0.5  <=>  3*inter > aa+ab+eps.
// chunk-major output: adjC[(b*32+c)*2048 + j] = uint2{cols c*64..+31, +32..+63}.
__global__ __launch_bounds__(512) void k2_adj(
    const float4* __restrict__ boxs, uint2* __restrict__ adjC)
{
  const int b = blockIdx.x & 7;
  const int rg = blockIdx.x >> 3;      // 0..31
  const int tid = threadIdx.x;         // 0..511
  const int lane = tid & 63;
  const int w = tid >> 6;              // wave 0..7 -> cols w*256..+256
  __shared__ float4 bs[BN];            // 32 KB

  const float4* B = boxs + b * BN;
  for (int k = tid; k < BN; k += 512) bs[k] = B[k];
  __syncthreads();

  const int row = rg * 64 + lane;
  const float4 rb = bs[row];
  const float aaE = (rb.z - rb.x) * (rb.w - rb.y) + EPSF;

  unsigned out[8];
#pragma unroll
  for (int ww = 0; ww < 8; ++ww) {
    unsigned bits = 0;
    const int j0 = w * 256 + ww * 32;
#pragma unroll
    for (int jj = 0; jj < 32; ++jj) {
      float4 bj = bs[j0 + jj];                 // broadcast read
      float lx = fmaxf(rb.x, bj.x), ly = fmaxf(rb.y, bj.y);
      float hx = fminf(rb.z, bj.z), hy = fminf(rb.w, bj.w);
      float wd = fmaxf(hx - lx, 0.f), ht = fmaxf(hy - ly, 0.f);
      float inter = wd * ht;
      float ab = (bj.z - bj.x) * (bj.w - bj.y);
      bits |= (3.0f * inter > aaE + ab) ? (1u << jj) : 0u;
    }
    out[ww] = bits;
  }
  uint2* CO = adjC + (size_t)b * 32 * 2048;
#pragma unroll
  for (int k = 0; k < 4; ++k) {
    int c = w * 4 + k;
    CO[(size_t)c * 2048 + row] = make_uint2(out[2 * k], out[2 * k + 1]);
  }
}

// ------------------------- K3a: streaming-sup greedy resolve (1 wave/batch)
// 3-deep prefetch: chunk c uses buf[c%3]; prefetch c+3 issued right after use.
__global__ __launch_bounds__(64, 1) void k3a_resolve(
    const short* __restrict__ gtss, const uint2* __restrict__ adjC,
    unsigned* __restrict__ pm_g, int* __restrict__ fpr_g,
    unsigned short* __restrict__ ev_g, int* __restrict__ meta_g,
    float* __restrict__ qs_g, int* __restrict__ qc_g, unsigned* __restrict__ hp_g)
{
  const int b = blockIdx.x;
  const int lane = threadIdx.x;       // 0..63
  __shared__ unsigned pm_lds[64];
  __shared__ int fpr_s[64];

  const uint2* Cb = adjC + (size_t)b * 32 * 2048;

  // act word: bit k = rank k*64+lane is positive
  unsigned act = 0;
#pragma unroll
  for (int k = 0; k < 32; ++k)
    if (gtss[b * BN + k * 64 + lane] >= 0) act |= (1u << k);
  int npos = __popc(act);
  for (int o = 1; o < 64; o <<= 1) npos += __shfl_xor(npos, o);

  unsigned sup = 0;
  unsigned mypm = 0;
  int npick = 0;                      // wave-uniform

  uint2 bufA[32], bufB[32], bufC[32];
#pragma unroll
  for (int k = 0; k < 32; ++k) bufA[k] = Cb[(size_t)0 * 2048 + k * 64 + lane];
#pragma unroll
  for (int k = 0; k < 32; ++k) bufB[k] = Cb[(size_t)1 * 2048 + k * 64 + lane];
#pragma unroll
  for (int k = 0; k < 32; ++k) bufC[k] = Cb[(size_t)2 * 2048 + k * 64 + lane];

#define CHUNK(cc, BUF)                                                         \
  {                                                                            \
    unsigned mybit = ((act >> (cc)) & ~(sup >> (cc))) & 1u;                    \
    unsigned long long row64 =                                                 \
        ((unsigned long long)BUF[cc].y << 32) | (unsigned long long)BUF[cc].x; \
    unsigned long long pickw = 0ull;                                           \
    unsigned long long bal = __ballot(mybit != 0u);                            \
    while (bal) {                                                              \
      int bpos = (int)__ffsll(bal) - 1;                                        \
      pickw |= 1ull << bpos;                                                   \
      mybit &= ~(unsigned)((row64 >> bpos) & 1ull);                            \
      bal = __ballot(mybit != 0u);                                             \
    }                                                                          \
    if (pickw != 0ull) {                                                       \
      npick += (int)__popcll(pickw);                                           \
      unsigned pwlo = (unsigned)pickw;                                         \
      unsigned pwhi = (unsigned)(pickw >> 32);                                 \
      if (lane == 0) { pm_lds[2*(cc)] = pwlo; pm_lds[2*(cc)+1] = pwhi; }       \
      _Pragma("unroll")                                                        \
      for (int k = 0; k < 32; ++k) {                                           \
        unsigned hit = (BUF[k].x & pwlo) | (BUF[k].y & pwhi);                  \
        sup |= (hit != 0u) ? (1u << k) : 0u;                                   \
      }                                                                        \
    } else if (lane == 0) {                                                    \
      pm_lds[2*(cc)] = 0u; pm_lds[2*(cc)+1] = 0u;                              \
    }                                                                          \
    if ((cc) + 3 < 32) {                                                       \
      _Pragma("unroll")                                                        \
      for (int k = 0; k < 32; ++k)                                             \
        BUF[k] = Cb[(size_t)((cc) + 3) * 2048 + k * 64 + lane];                \
    }                                                                          \
  }

  CHUNK(0, bufA)  CHUNK(1, bufB)  CHUNK(2, bufC)  CHUNK(3, bufA)
  CHUNK(4, bufB)  CHUNK(5, bufC)  CHUNK(6, bufA)  CHUNK(7, bufB)
  CHUNK(8, bufC)  CHUNK(9, bufA)  CHUNK(10, bufB) CHUNK(11, bufC)
  CHUNK(12, bufA) CHUNK(13, bufB) CHUNK(14, bufC) CHUNK(15, bufA)
  CHUNK(16, bufB) CHUNK(17, bufC) CHUNK(18, bufA) CHUNK(19, bufB)
  CHUNK(20, bufC) CHUNK(21, bufA) CHUNK(22, bufB) CHUNK(23, bufC)
  CHUNK(24, bufA) CHUNK(25, bufB) CHUNK(26, bufC) CHUNK(27, bufA)
  CHUNK(28, bufB) CHUNK(29, bufC) CHUNK(30, bufA) CHUNK(31, bufB)
#undef CHUNK

  fpr_s[lane] = INT_MAX;
  __syncthreads();

  // epilogue: prefix popcounts, ev2rank, fpr
  mypm = pm_lds[lane];                // word covers ranks lane*32..+31
  int pre = 0;
  for (int w = 0; w < lane; ++w) pre += __popc(pm_lds[w]);
  {
    unsigned w = mypm; int e = pre;
    while (w) {
      int bpos = __ffs(w) - 1; w &= w - 1;
      int rank = lane * 32 + bpos;
      ev_g[b * BN + e] = (unsigned short)rank;
      int g = (int)gtss[b * BN + rank];
      atomicMin(&fpr_s[g], rank);
      e++;
    }
  }
  __syncthreads();

  pm_g[b * 64 + lane] = mypm;
  fpr_g[b * 64 + lane] = fpr_s[lane];
  hp_g[b * 64 + lane] = 0u;
  if (lane == 0) {
    meta_g[b * 4 + 0] = npick;
    meta_g[b * 4 + 1] = 0;        // lastrem
    meta_g[b * 4 + 2] = npos;
  }
  for (int k = 0; k < 32; ++k) {
    int j = lane + k * 64;
    qs_g[b * BN + j] = 0.f;
    qc_g[b * BN + j] = 0;
  }
}

// ---------------------------- K3b: parallel per-box event contributions
__global__ __launch_bounds__(256) void k3b_events(
    const short* __restrict__ gtss, const float* __restrict__ pers,
    const uint2* __restrict__ adjC, const unsigned* __restrict__ pm_g,
    const int* __restrict__ fpr_g, int* __restrict__ meta_g,
    float* __restrict__ qs_g, int* __restrict__ qc_g, unsigned* __restrict__ hp_g)
{
  const int blk = blockIdx.x;       // 8 batches * 8 segments
  const int b = blk & 7;
  const int seg = blk >> 3;
  const int tid = threadIdx.x;
  __shared__ unsigned pm_s[64];
  __shared__ unsigned pre_s[64];
  __shared__ short gts_s[BN];       // 4 KB

  if (tid < 64) pm_s[tid] = pm_g[b * 64 + tid];
  for (int k = 0; k < 4; ++k)
    ((int*)gts_s)[tid + 256 * k] = ((const int*)(gtss + b * BN))[tid + 256 * k];
  __syncthreads();
  if (tid < 64) {
    int s = 0;
    for (int w = 0; w < tid; ++w) s += __popc(pm_s[w]);
    pre_s[tid] = (unsigned)s;
  }
  __syncthreads();

  const int j = seg * 256 + tid;
  const uint2* Cj = adjC + (size_t)b * 32 * 2048 + j;
  int frank = -1;
#pragma unroll
  for (int c = 0; c < 32; ++c) {
    uint2 v = Cj[(size_t)c * 2048];
    unsigned m0 = v.x & pm_s[2 * c];
    unsigned m1 = v.y & pm_s[2 * c + 1];
    if (frank < 0 && m0) frank = c * 64 + __ffs(m0) - 1;
    if (frank < 0 && m1) frank = c * 64 + 32 + __ffs(m1) - 1;
  }

  int gj = (int)gts_s[j];
  if (frank >= 0 && frank != j && gj >= 0) {
    int e = (int)pre_s[frank >> 5] + __popc(pm_s[frank >> 5] & ((1u << (frank & 31)) - 1u));
    int P = meta_g[b * 4 + 0];
    if (e == P - 1) atomicOr(&meta_g[b * 4 + 1], 1);
    int gt = (int)gts_s[frank];
    if (gj != gt) {
      atomicOr(&hp_g[b * 64 + (e >> 5)], 1u << (e & 31));
      if (fpr_g[b * 64 + gj] > frank) {
        atomicAdd(&qs_g[b * BN + e], pers[b * BN + j]);
        atomicAdd(&qc_g[b * BN + e], 1);
      }
    }
  }
}

// ---------------------------- K3c: event pass, one block per batch
__global__ __launch_bounds__(256) void k3c_loss(
    const float4* __restrict__ boxs, const float* __restrict__ scs,
    const short* __restrict__ gtss, const unsigned short* __restrict__ ev_g,
    const int* __restrict__ fpr_g, const int* __restrict__ meta_g,
    const float* __restrict__ qs_g, const int* __restrict__ qc_g,
    const unsigned* __restrict__ hp_g, float* __restrict__ bp)
{
  const int b = blockIdx.x;
  const int tid = threadIdx.x;
  const int lane = tid & 63;
  const int wave = tid >> 6;
  __shared__ float redp[4][4];

  const int P = meta_g[b * 4 + 0];
  const int lastrem = meta_g[b * 4 + 1];
  const int npos = meta_g[b * 4 + 2];
  float pull_l = 0.f, pcl = 0.f, push_l = 0.f, pshl = 0.f;
  for (int t = tid; t < P; t += 256) {
    int r = (int)ev_g[b * BN + t];
    int g = (int)gtss[b * BN + r];
    int fp = fpr_g[b * 64 + g];
    bool seen = (fp < r);
    bool hr = (t < P - 1) || (lastrem != 0);
    if (seen) {
      pcl += 1.f;
      if (hr) {
        float4 bA = boxs[b * BN + fp];
        float4 bB = boxs[b * BN + r];
        float io = iou_box(bA, bB);
        pull_l += -logf(1.f - THR + fmaxf(io, EPSF)) * scs[b * BN + r];
      }
    }
    if (hr && ((hp_g[b * 64 + (t >> 5)] >> (t & 31)) & 1u)) {
      pshl += 1.f;
      push_l += qs_g[b * BN + t] / ((float)qc_g[b * BN + t] + EPSF);
    }
  }
  for (int o = 1; o < 64; o <<= 1) {
    pull_l += __shfl_xor(pull_l, o);
    pcl    += __shfl_xor(pcl, o);
    push_l += __shfl_xor(push_l, o);
    pshl   += __shfl_xor(pshl, o);
  }
  if (lane == 0) { redp[wave][0] = pull_l; redp[wave][1] = pcl; redp[wave][2] = push_l; redp[wave][3] = pshl; }
  __syncthreads();
  if (tid == 0) {
    float Ps = 0.f, Pc = 0.f, Ss = 0.f, Sc = 0.f;
    for (int w = 0; w < 4; ++w) { Ps += redp[w][0]; Pc += redp[w][1]; Ss += redp[w][2]; Sc += redp[w][3]; }
    float gate = (npos > 1) ? 1.f : 0.f;
    bp[b * 2 + 0] = gate * Ss / (Sc + EPSF);   // push
    bp[b * 2 + 1] = gate * Ps / (Pc + EPSF);   // pull
  }
}

__global__ void nms_finalize_kernel(const float* __restrict__ bp, float* __restrict__ out, int nb) {
  if (threadIdx.x == 0 && blockIdx.x == 0) {
    float ps = 0.f, pl = 0.f;
    for (int b = 0; b < nb; ++b) { ps += bp[2 * b]; pl += bp[2 * b + 1]; }
    float inv = 1.f / (float)nb;
    out[0] = ps * inv * PUSH_W;
    out[1] = pl * inv * PULL_W;
  }
}

// =============================== fallback path (round-1 kernel, proven) =====
constexpr int NT = 256;
constexpr int PT = BN / NT;
constexpr int NW = NT / 64;

__global__ __launch_bounds__(NT) void nms_loss_kernel(
    const int* __restrict__ gti_all, const float* __restrict__ gtb_all,
    const float* __restrict__ prop_all, float* __restrict__ out_bp)
{
  const int b = blockIdx.x;
  const int tid = threadIdx.x;
  const int lane = tid & 63;
  const int wave = tid >> 6;

  __shared__ float4 box[BN];
  __shared__ float sc[BN];
  __shared__ float per[BN];
  __shared__ int gts[BN];
  __shared__ unsigned char act[BN];
  __shared__ int rec[BG];
  __shared__ float rs[NW];
  __shared__ int ri[NW];
  __shared__ int rrem[NW];
  __shared__ int rqc[NW];
  __shared__ float rqs[NW];
  __shared__ int rany[NW];
  __shared__ int sh_nact;
  __shared__ int sh_ig;
  __shared__ float4 sh_ibox;

  const int* gti = gti_all + b * BN;
  const float* GB = gtb_all + b * BG * 4;
  const float* P = prop_all + (size_t)b * BN * 5;

  int local_pos = 0;
  for (int k = 0; k < PT; ++k) {
    int j = tid + k * NT;
    float x1 = P[j * 5 + 0], y1 = P[j * 5 + 1];
    float x2 = P[j * 5 + 2], y2 = P[j * 5 + 3];
    float s = P[j * 5 + 4];
    box[j] = make_float4(x1, y1, x2, y2);
    sc[j] = s;
    int g = gti[j];
    gts[j] = g;
    unsigned char a = (g >= 0) ? 1 : 0;
    act[j] = a;
    local_pos += a;
    float pv = 0.f;
    if (g >= 0) {
      float4 gb = make_float4(GB[g * 4], GB[g * 4 + 1], GB[g * 4 + 2], GB[g * 4 + 3]);
      float i2 = iou_box(gb, make_float4(x1, y1, x2, y2));
      pv = -logf(EPSF + i2) * s;
    }
    per[j] = pv;
  }
  if (tid < BG) rec[tid] = -1;
  for (int off = 32; off; off >>= 1) local_pos += __shfl_down(local_pos, off);
  if (lane == 0) rrem[wave] = local_pos;
  __syncthreads();
  int n_pos = 0;
  if (tid == 0) {
    for (int w = 0; w < NW; ++w) n_pos += rrem[w];
    sh_nact = n_pos;
  }
  float pull_sum = 0.f, push_sum = 0.f, pull_cnt = 0.f, push_cnt = 0.f;
  int t0_hasrem = 0;
  __syncthreads();

  while (true) {
    int nact = sh_nact;
    if (nact <= 0) break;
    float bs = -INFINITY;
    int bi = BN;
    for (int k = 0; k < PT; ++k) {
      int j = tid + k * NT;
      if (act[j]) {
        float s = sc[j];
        if (s > bs || (s == bs && j < bi)) { bs = s; bi = j; }
      }
    }
    for (int off = 32; off; off >>= 1) {
      float os = __shfl_down(bs, off);
      int oi = __shfl_down(bi, off);
      if (os > bs || (os == bs && oi < bi)) { bs = os; bi = oi; }
    }
    if (lane == 0) { rs[wave] = bs; ri[wave] = bi; }
    __syncthreads();
    if (tid == 0) {
      float cs = rs[0]; int ci = ri[0];
      for (int w = 1; w < NW; ++w)
        if (rs[w] > cs || (rs[w] == cs && ri[w] < ci)) { cs = rs[w]; ci = ri[w]; }
      int i = ci;
      int ig = gts[i];
      act[i] = 0;
      t0_hasrem = (nact - 1 > 0);
      int r = rec[ig];
      if (r >= 0) {
        pull_cnt += 1.f;
        if (t0_hasrem) {
          float i2 = iou_box(box[r], box[i]);
          float m = fmaxf(i2, EPSF);
          pull_sum += -logf(1.f - THR + m) * sc[i];
        }
      } else {
        rec[ig] = i;
      }
      sh_ig = ig; sh_ibox = box[i];
    }
    __syncthreads();
    float4 ib = sh_ibox;
    int igx = sh_ig;
    int removed = 0, qcc = 0, anyp = 0;
    float qss = 0.f;
    for (int k = 0; k < PT; ++k) {
      int j = tid + k * NT;
      if (act[j]) {
        float i2 = iou_box(ib, box[j]);
        if (i2 > THR) {
          act[j] = 0;
          removed++;
          int gj = gts[j];
          if (gj != igx) {
            anyp = 1;
            if (rec[gj] < 0) { qcc++; qss += per[j]; }
          }
        }
      }
    }
    for (int off = 32; off; off >>= 1) {
      removed += __shfl_down(removed, off);
      qcc += __shfl_down(qcc, off);
      qss += __shfl_down(qss, off);
      anyp |= __shfl_down(anyp, off);
    }
    if (lane == 0) { rrem[wave] = removed; rqc[wave] = qcc; rqs[wave] = qss; rany[wave] = anyp; }
    __syncthreads();
    if (tid == 0) {
      int rm = 0, qct = 0, ap = 0; float qst = 0.f;
      for (int w = 0; w < NW; ++w) { rm += rrem[w]; qct += rqc[w]; qst += rqs[w]; ap |= rany[w]; }
      sh_nact = nact - 1 - rm;
      if (t0_hasrem && ap) {
        push_sum += qst / ((float)qct + EPSF);
        push_cnt += 1.f;
      }
    }
    __syncthreads();
  }

  if (tid == 0) {
    float gate = (n_pos > 1) ? 1.f : 0.f;
    out_bp[b * 2 + 0] = gate * push_sum / (push_cnt + EPSF);
    out_bp[b * 2 + 1] = gate * pull_sum / (pull_cnt + EPSF);
  }
}

// ============================================================== launch =====
extern "C" void kernel_launch(void* const* d_in, const int* in_sizes, int n_in,
                              void* d_out, int out_size, void* d_ws, size_t ws_size,
                              hipStream_t stream) {
  const int* gti = (const int*)d_in[1];
  const float* gtb = (const float*)d_in[2];
  const float* props = (const float*)d_in[3];
  float* out = (float*)d_out;
  const int nb = in_sizes[1] / BN;   // 8

  // ws layout (bytes)
  const size_t off_adj  = 0;                                    // nb*32*2048*8
  const size_t off_box  = off_adj  + (size_t)nb * BN * 64 * 4;  // nb*BN*16
  const size_t off_per  = off_box  + (size_t)nb * BN * 16;      // nb*BN*4
  const size_t off_sc   = off_per  + (size_t)nb * BN * 4;       // nb*BN*4
  const size_t off_qs   = off_sc   + (size_t)nb * BN * 4;       // nb*BN*4
  const size_t off_qc   = off_qs   + (size_t)nb * BN * 4;       // nb*BN*4
  const size_t off_gts  = off_qc   + (size_t)nb * BN * 4;       // nb*BN*2
  const size_t off_ev   = off_gts  + (size_t)nb * BN * 2;       // nb*BN*2
  const size_t off_pm   = off_ev   + (size_t)nb * BN * 2;       // nb*64*4
  const size_t off_fpr  = off_pm   + (size_t)nb * 64 * 4;       // nb*64*4
  const size_t off_hp   = off_fpr  + (size_t)nb * 64 * 4;       // nb*64*4
  const size_t off_meta = off_hp   + (size_t)nb * 64 * 4;       // nb*4*4
  const size_t off_bp   = off_meta + (size_t)nb * 4 * 4;        // nb*2*4
  const size_t needed   = off_bp   + (size_t)nb * 2 * 4;

  if (ws_size >= needed && nb == 8) {
    char* ws = (char*)d_ws;
    uint2* adjC = (uint2*)(ws + off_adj);
    float4* boxs = (float4*)(ws + off_box);
    float* pers = (float*)(ws + off_per);
    float* scs = (float*)(ws + off_sc);
    float* qs = (float*)(ws + off_qs);
    int* qc = (int*)(ws + off_qc);
    short* gtss = (short*)(ws + off_gts);
    unsigned short* ev = (unsigned short*)(ws + off_ev);
    unsigned* pm = (unsigned*)(ws + off_pm);
    int* fpr = (int*)(ws + off_fpr);
    unsigned* hp = (unsigned*)(ws + off_hp);
    int* meta = (int*)(ws + off_meta);
    float* bp = (float*)(ws + off_bp);

    k1_sort<<<nb * 8, 256, 0, stream>>>(gti, gtb, props, boxs, pers, gtss, scs);
    k2_adj<<<nb * 32, 512, 0, stream>>>(boxs, adjC);
    k3a_resolve<<<nb, 64, 0, stream>>>(gtss, adjC, pm, fpr, ev, meta, qs, qc, hp);
    k3b_events<<<nb * 8, 256, 0, stream>>>(gtss, pers, adjC, pm, fpr, meta, qs, qc, hp);
    k3c_loss<<<nb, 256, 0, stream>>>(boxs, scs, gtss, ev, fpr, meta, qs, qc, hp, bp);
    nms_finalize_kernel<<<1, 64, 0, stream>>>(bp, out, nb);
  } else {
    float* bp = (float*)d_ws;
    nms_loss_kernel<<<nb, NT, 0, stream>>>(gti, gtb, props, bp);
    nms_finalize_kernel<<<1, 64, 0, stream>>>(bp, out, nb);
  }
}

// Round 9
// 98.281 us; speedup vs baseline: 1.3604x; 1.1931x over previous
//
#include <hip/hip_runtime.h>
#include <math.h>
#include <limits.h>

#define EPSF 1e-6f
#define THR 0.5f
#define PUSH_W 1.0f
#define PULL_W 1.0f

constexpr int BN = 2048;    // proposals per batch
constexpr int BG = 64;      // gt boxes per batch

__device__ __forceinline__ float iou_box(float4 a, float4 b) {
  float aa = (a.z - a.x) * (a.w - a.y);
  float ab = (b.z - b.x) * (b.w - b.y);
  float w = fmaxf(fminf(a.z, b.z) - fmaxf(a.x, b.x), 0.f);
  float h = fmaxf(fminf(a.w, b.w) - fmaxf(a.y, b.y), 0.f);
  float inter = w * h;
  return inter / (aa + ab - inter + EPSF);
}

// -------------------------------------------------- K1: rank-by-count sort
__global__ __launch_bounds__(256) void k1_sort(
    const int* __restrict__ gti_all, const float* __restrict__ gtb_all,
    const float* __restrict__ prop_all,
    float4* __restrict__ boxs, float* __restrict__ pers,
    short* __restrict__ gtss, float* __restrict__ scs)
{
  const int b = blockIdx.x & 7;        // batch
  const int rg = blockIdx.x >> 3;      // row group
  const int tid = threadIdx.x;
  __shared__ unsigned long long key[BN];   // 16 KB

  const float* P = prop_all + (size_t)b * BN * 5;
  const int* gti = gti_all + b * BN;
  const float* GB = gtb_all + b * BG * 4;

  for (int k = 0; k < 8; ++k) {
    int j = tid + k * 256;
    unsigned bits = __float_as_uint(P[j * 5 + 4]);
    key[j] = ((unsigned long long)bits << 32) | (unsigned)(BN - 1 - j);
  }
  __syncthreads();

  const int r = rg * 256 + tid;
  const unsigned long long myk = key[r];
  int rank = 0;
  const ulonglong2* K2 = (const ulonglong2*)key;
#pragma unroll 8
  for (int j = 0; j < BN / 2; ++j) {
    ulonglong2 kk = K2[j];
    rank += (kk.x > myk) ? 1 : 0;
    rank += (kk.y > myk) ? 1 : 0;
  }

  int idx = (BN - 1) - (int)(myk & 0xffffffffu);
  float x1 = P[idx * 5 + 0], y1 = P[idx * 5 + 1];
  float x2 = P[idx * 5 + 2], y2 = P[idx * 5 + 3];
  float s = __uint_as_float((unsigned)(myk >> 32));
  int g = gti[idx];
  float4 bx = make_float4(x1, y1, x2, y2);
  boxs[b * BN + rank] = bx;
  scs[b * BN + rank] = s;
  gtss[b * BN + rank] = (short)g;
  float pv = 0.f;
  if (g >= 0) {
    float4 gb = make_float4(GB[g * 4 + 0], GB[g * 4 + 1], GB[g * 4 + 2], GB[g * 4 + 3]);
    float i2 = iou_box(gb, bx);
    pv = -logf(EPSF + i2) * s;
  }
  pers[b * BN + rank] = pv;
}

// ------------------------------------------------------------- K2: adjacency
// Zero-LDS: rows per-lane in VGPRs; columns via wave-uniform (readfirstlane)
// scalar-cache loads. Branchless predicate: iou>0.5 <=> 3*inter > aa+ab+eps.
// chunk-major: adjC[(b*32+c)*2048 + j] = uint2{cols c*64..+31, +32..+63}.
__global__ __launch_bounds__(512) void k2_adj(
    const float4* __restrict__ boxs, uint2* __restrict__ adjC)
{
  const int b = blockIdx.x & 7;
  const int rg = blockIdx.x >> 3;      // 0..31
  const int tid = threadIdx.x;         // 0..511
  const int lane = tid & 63;
  const int w = tid >> 6;              // wave 0..7 -> cols w*256..+256
  const int wu = __builtin_amdgcn_readfirstlane(w);   // force SGPR

  const float4* B = boxs + b * BN;
  const int row = rg * 64 + lane;
  const float4 rb = B[row];            // per-lane row box, coalesced
  const float aaE = (rb.z - rb.x) * (rb.w - rb.y) + EPSF;
  const float4* Bc = B + wu * 256;     // wave-uniform column base

  unsigned out[8];
#pragma unroll
  for (int ww = 0; ww < 8; ++ww) {
    unsigned bits = 0;
#pragma unroll
    for (int jj = 0; jj < 32; ++jj) {
      float4 bj = Bc[ww * 32 + jj];    // uniform address -> s_load / broadcast
      float lx = fmaxf(rb.x, bj.x), ly = fmaxf(rb.y, bj.y);
      float hx = fminf(rb.z, bj.z), hy = fminf(rb.w, bj.w);
      float wd = fmaxf(hx - lx, 0.f), ht = fmaxf(hy - ly, 0.f);
      float inter = wd * ht;
      float ab = (bj.z - bj.x) * (bj.w - bj.y);
      bits |= (3.0f * inter > aaE + ab) ? (1u << jj) : 0u;
    }
    out[ww] = bits;
  }
  uint2* CO = adjC + (size_t)b * 32 * 2048;
#pragma unroll
  for (int k = 0; k < 4; ++k) {
    int c = wu * 4 + k;
    CO[(size_t)c * 2048 + row] = make_uint2(out[2 * k], out[2 * k + 1]);
  }
}

// ------------- K3a: producer/consumer greedy resolve (4 waves per batch)
// Waves 1-3 rotate prefetching chunk c+2 into LDS slot[(c+2)%3]; wave 0
// resolves chunk c from slot[c%3]. 2-barrier slack hides L3 latency.
__global__ __launch_bounds__(256, 1) void k3a_resolve(
    const short* __restrict__ gtss, const uint2* __restrict__ adjC,
    unsigned* __restrict__ pm_g, int* __restrict__ fpr_g,
    unsigned short* __restrict__ ev_g, int* __restrict__ meta_g,
    float* __restrict__ qs_g, int* __restrict__ qc_g, unsigned* __restrict__ hp_g)
{
  const int b = blockIdx.x;
  const int tid = threadIdx.x;
  const int lane = tid & 63;
  const int wave = tid >> 6;
  __shared__ uint2 slot[3][2048];       // 48 KB
  __shared__ unsigned pm_lds[64];
  __shared__ int fpr_s[64];
  __shared__ int npos_s, npick_s;

  const uint2* Cb = adjC + (size_t)b * 32 * 2048;

  // prologue: wave1 -> chunk0/slot0, wave2 -> chunk1/slot1
  if (wave == 1 || wave == 2) {
    const int c = wave - 1;
#pragma unroll
    for (int k = 0; k < 32; ++k)
      slot[c][k * 64 + lane] = Cb[(size_t)c * 2048 + k * 64 + lane];
  }
  unsigned act = 0;
  if (wave == 0) {
#pragma unroll
    for (int k = 0; k < 32; ++k)
      if (gtss[b * BN + k * 64 + lane] >= 0) act |= (1u << k);
    int npos = __popc(act);
    for (int o = 1; o < 64; o <<= 1) npos += __shfl_xor(npos, o);
    if (lane == 0) npos_s = npos;
  }
  __syncthreads();

  unsigned sup = 0;
  int npick = 0;                        // live only in wave 0
  for (int c = 0; c < 32; ++c) {
    // producer: load chunk c+2 into slot[(c+2)%3] (read at step c+2)
    if (wave == 1 + (c % 3)) {
      const int cn = c + 2;
      if (cn < 32) {
        uint2* S = slot[cn % 3];
#pragma unroll
        for (int k = 0; k < 32; ++k)
          S[k * 64 + lane] = Cb[(size_t)cn * 2048 + k * 64 + lane];
      }
    }
    // consumer: resolve chunk c
    if (wave == 0) {
      const uint2* S = slot[c % 3];
      uint2 d = S[c * 64 + lane];       // diag row: rank c*64+lane, cols c*64..+63
      unsigned mybit = ((act >> c) & ~(sup >> c)) & 1u;
      unsigned long long row64 = ((unsigned long long)d.y << 32) | (unsigned long long)d.x;
      unsigned long long pickw = 0ull;
      unsigned long long bal = __ballot(mybit != 0u);
      while (bal) {
        int bpos = (int)__ffsll(bal) - 1;
        pickw |= 1ull << bpos;
        mybit &= ~(unsigned)((row64 >> bpos) & 1ull);
        bal = __ballot(mybit != 0u);
      }
      if (lane == 0) {
        pm_lds[2 * c] = (unsigned)pickw;
        pm_lds[2 * c + 1] = (unsigned)(pickw >> 32);
      }
      if (pickw != 0ull) {
        npick += (int)__popcll(pickw);
        unsigned pwlo = (unsigned)pickw, pwhi = (unsigned)(pickw >> 32);
#pragma unroll
        for (int k = 0; k < 32; ++k) {
          uint2 v = S[k * 64 + lane];
          unsigned hit = (v.x & pwlo) | (v.y & pwhi);
          sup |= (hit != 0u) ? (1u << k) : 0u;
        }
      }
    }
    __syncthreads();
  }
  if (wave == 0 && lane == 0) npick_s = npick;
  if (tid < 64) fpr_s[tid] = INT_MAX;
  __syncthreads();

  // epilogue: prefix popcounts, ev2rank, fpr (wave 0)
  if (wave == 0) {
    unsigned mypm = pm_lds[lane];       // word covers ranks lane*32..+31
    int pre = 0;
    for (int w2 = 0; w2 < lane; ++w2) pre += __popc(pm_lds[w2]);
    unsigned wbits = mypm; int e = pre;
    while (wbits) {
      int bpos = __ffs(wbits) - 1; wbits &= wbits - 1;
      int rank = lane * 32 + bpos;
      ev_g[b * BN + e] = (unsigned short)rank;
      atomicMin(&fpr_s[(int)gtss[b * BN + rank]], rank);
      e++;
    }
  }
  __syncthreads();

  if (tid < 64) {
    pm_g[b * 64 + tid] = pm_lds[tid];
    fpr_g[b * 64 + tid] = fpr_s[tid];
    hp_g[b * 64 + tid] = 0u;
  }
  if (tid == 0) {
    meta_g[b * 4 + 0] = npick_s;
    meta_g[b * 4 + 1] = 0;        // lastrem
    meta_g[b * 4 + 2] = npos_s;
  }
  for (int k = tid; k < BN; k += 256) {
    qs_g[b * BN + k] = 0.f;
    qc_g[b * BN + k] = 0;
  }
}

// ---------------------------- K3b: parallel per-box event contributions
__global__ __launch_bounds__(256) void k3b_events(
    const short* __restrict__ gtss, const float* __restrict__ pers,
    const uint2* __restrict__ adjC, const unsigned* __restrict__ pm_g,
    const int* __restrict__ fpr_g, int* __restrict__ meta_g,
    float* __restrict__ qs_g, int* __restrict__ qc_g, unsigned* __restrict__ hp_g)
{
  const int blk = blockIdx.x;       // 8 batches * 8 segments
  const int b = blk & 7;
  const int seg = blk >> 3;
  const int tid = threadIdx.x;
  __shared__ unsigned pm_s[64];
  __shared__ unsigned pre_s[64];
  __shared__ short gts_s[BN];       // 4 KB

  if (tid < 64) pm_s[tid] = pm_g[b * 64 + tid];
  for (int k = 0; k < 4; ++k)
    ((int*)gts_s)[tid + 256 * k] = ((const int*)(gtss + b * BN))[tid + 256 * k];
  __syncthreads();
  if (tid < 64) {
    int s = 0;
    for (int w = 0; w < tid; ++w) s += __popc(pm_s[w]);
    pre_s[tid] = (unsigned)s;
  }
  __syncthreads();

  const int j = seg * 256 + tid;
  const uint2* Cj = adjC + (size_t)b * 32 * 2048 + j;
  int frank = -1;
#pragma unroll
  for (int c = 0; c < 32; ++c) {
    uint2 v = Cj[(size_t)c * 2048];
    unsigned m0 = v.x & pm_s[2 * c];
    unsigned m1 = v.y & pm_s[2 * c + 1];
    if (frank < 0 && m0) frank = c * 64 + __ffs(m0) - 1;
    if (frank < 0 && m1) frank = c * 64 + 32 + __ffs(m1) - 1;
  }

  int gj = (int)gts_s[j];
  if (frank >= 0 && frank != j && gj >= 0) {
    int e = (int)pre_s[frank >> 5] + __popc(pm_s[frank >> 5] & ((1u << (frank & 31)) - 1u));
    int P = meta_g[b * 4 + 0];
    if (e == P - 1) atomicOr(&meta_g[b * 4 + 1], 1);
    int gt = (int)gts_s[frank];
    if (gj != gt) {
      atomicOr(&hp_g[b * 64 + (e >> 5)], 1u << (e & 31));
      if (fpr_g[b * 64 + gj] > frank) {
        atomicAdd(&qs_g[b * BN + e], pers[b * BN + j]);
        atomicAdd(&qc_g[b * BN + e], 1);
      }
    }
  }
}

// ---------------------------- K3c: event pass, one block per batch
__global__ __launch_bounds__(256) void k3c_loss(
    const float4* __restrict__ boxs, const float* __restrict__ scs,
    const short* __restrict__ gtss, const unsigned short* __restrict__ ev_g,
    const int* __restrict__ fpr_g, const int* __restrict__ meta_g,
    const float* __restrict__ qs_g, const int* __restrict__ qc_g,
    const unsigned* __restrict__ hp_g, float* __restrict__ bp)
{
  const int b = blockIdx.x;
  const int tid = threadIdx.x;
  const int lane = tid & 63;
  const int wave = tid >> 6;
  __shared__ float redp[4][4];

  const int P = meta_g[b * 4 + 0];
  const int lastrem = meta_g[b * 4 + 1];
  const int npos = meta_g[b * 4 + 2];
  float pull_l = 0.f, pcl = 0.f, push_l = 0.f, pshl = 0.f;
  for (int t = tid; t < P; t += 256) {
    int r = (int)ev_g[b * BN + t];
    int g = (int)gtss[b * BN + r];
    int fp = fpr_g[b * 64 + g];
    bool seen = (fp < r);
    bool hr = (t < P - 1) || (lastrem != 0);
    if (seen) {
      pcl += 1.f;
      if (hr) {
        float4 bA = boxs[b * BN + fp];
        float4 bB = boxs[b * BN + r];
        float io = iou_box(bA, bB);
        pull_l += -logf(1.f - THR + fmaxf(io, EPSF)) * scs[b * BN + r];
      }
    }
    if (hr && ((hp_g[b * 64 + (t >> 5)] >> (t & 31)) & 1u)) {
      pshl += 1.f;
      push_l += qs_g[b * BN + t] / ((float)qc_g[b * BN + t] + EPSF);
    }
  }
  for (int o = 1; o < 64; o <<= 1) {
    pull_l += __shfl_xor(pull_l, o);
    pcl    += __shfl_xor(pcl, o);
    push_l += __shfl_xor(push_l, o);
    pshl   += __shfl_xor(pshl, o);
  }
  if (lane == 0) { redp[wave][0] = pull_l; redp[wave][1] = pcl; redp[wave][2] = push_l; redp[wave][3] = pshl; }
  __syncthreads();
  if (tid == 0) {
    float Ps = 0.f, Pc = 0.f, Ss = 0.f, Sc = 0.f;
    for (int w = 0; w < 4; ++w) { Ps += redp[w][0]; Pc += redp[w][1]; Ss += redp[w][2]; Sc += redp[w][3]; }
    float gate = (npos > 1) ? 1.f : 0.f;
    bp[b * 2 + 0] = gate * Ss / (Sc + EPSF);   // push
    bp[b * 2 + 1] = gate * Ps / (Pc + EPSF);   // pull
  }
}

__global__ void nms_finalize_kernel(const float* __restrict__ bp, float* __restrict__ out, int nb) {
  if (threadIdx.x == 0 && blockIdx.x == 0) {
    float ps = 0.f, pl = 0.f;
    for (int b = 0; b < nb; ++b) { ps += bp[2 * b]; pl += bp[2 * b + 1]; }
    float inv = 1.f / (float)nb;
    out[0] = ps * inv * PUSH_W;
    out[1] = pl * inv * PULL_W;
  }
}

// =============================== fallback path (round-1 kernel, proven) =====
constexpr int NT = 256;
constexpr int PT = BN / NT;
constexpr int NW = NT / 64;

__global__ __launch_bounds__(NT) void nms_loss_kernel(
    const int* __restrict__ gti_all, const float* __restrict__ gtb_all,
    const float* __restrict__ prop_all, float* __restrict__ out_bp)
{
  const int b = blockIdx.x;
  const int tid = threadIdx.x;
  const int lane = tid & 63;
  const int wave = tid >> 6;

  __shared__ float4 box[BN];
  __shared__ float sc[BN];
  __shared__ float per[BN];
  __shared__ int gts[BN];
  __shared__ unsigned char act[BN];
  __shared__ int rec[BG];
  __shared__ float rs[NW];
  __shared__ int ri[NW];
  __shared__ int rrem[NW];
  __shared__ int rqc[NW];
  __shared__ float rqs[NW];
  __shared__ int rany[NW];
  __shared__ int sh_nact;
  __shared__ int sh_ig;
  __shared__ float4 sh_ibox;

  const int* gti = gti_all + b * BN;
  const float* GB = gtb_all + b * BG * 4;
  const float* P = prop_all + (size_t)b * BN * 5;

  int local_pos = 0;
  for (int k = 0; k < PT; ++k) {
    int j = tid + k * NT;
    float x1 = P[j * 5 + 0], y1 = P[j * 5 + 1];
    float x2 = P[j * 5 + 2], y2 = P[j * 5 + 3];
    float s = P[j * 5 + 4];
    box[j] = make_float4(x1, y1, x2, y2);
    sc[j] = s;
    int g = gti[j];
    gts[j] = g;
    unsigned char a = (g >= 0) ? 1 : 0;
    act[j] = a;
    local_pos += a;
    float pv = 0.f;
    if (g >= 0) {
      float4 gb = make_float4(GB[g * 4], GB[g * 4 + 1], GB[g * 4 + 2], GB[g * 4 + 3]);
      float i2 = iou_box(gb, make_float4(x1, y1, x2, y2));
      pv = -logf(EPSF + i2) * s;
    }
    per[j] = pv;
  }
  if (tid < BG) rec[tid] = -1;
  for (int off = 32; off; off >>= 1) local_pos += __shfl_down(local_pos, off);
  if (lane == 0) rrem[wave] = local_pos;
  __syncthreads();
  int n_pos = 0;
  if (tid == 0) {
    for (int w = 0; w < NW; ++w) n_pos += rrem[w];
    sh_nact = n_pos;
  }
  float pull_sum = 0.f, push_sum = 0.f, pull_cnt = 0.f, push_cnt = 0.f;
  int t0_hasrem = 0;
  __syncthreads();

  while (true) {
    int nact = sh_nact;
    if (nact <= 0) break;
    float bs = -INFINITY;
    int bi = BN;
    for (int k = 0; k < PT; ++k) {
      int j = tid + k * NT;
      if (act[j]) {
        float s = sc[j];
        if (s > bs || (s == bs && j < bi)) { bs = s; bi = j; }
      }
    }
    for (int off = 32; off; off >>= 1) {
      float os = __shfl_down(bs, off);
      int oi = __shfl_down(bi, off);
      if (os > bs || (os == bs && oi < bi)) { bs = os; bi = oi; }
    }
    if (lane == 0) { rs[wave] = bs; ri[wave] = bi; }
    __syncthreads();
    if (tid == 0) {
      float cs = rs[0]; int ci = ri[0];
      for (int w = 1; w < NW; ++w)
        if (rs[w] > cs || (rs[w] == cs && ri[w] < ci)) { cs = rs[w]; ci = ri[w]; }
      int i = ci;
      int ig = gts[i];
      act[i] = 0;
      t0_hasrem = (nact - 1 > 0);
      int r = rec[ig];
      if (r >= 0) {
        pull_cnt += 1.f;
        if (t0_hasrem) {
          float i2 = iou_box(box[r], box[i]);
          float m = fmaxf(i2, EPSF);
          pull_sum += -logf(1.f - THR + m) * sc[i];
        }
      } else {
        rec[ig] = i;
      }
      sh_ig = ig; sh_ibox = box[i];
    }
    __syncthreads();
    float4 ib = sh_ibox;
    int igx = sh_ig;
    int removed = 0, qcc = 0, anyp = 0;
    float qss = 0.f;
    for (int k = 0; k < PT; ++k) {
      int j = tid + k * NT;
      if (act[j]) {
        float i2 = iou_box(ib, box[j]);
        if (i2 > THR) {
          act[j] = 0;
          removed++;
          int gj = gts[j];
          if (gj != igx) {
            anyp = 1;
            if (rec[gj] < 0) { qcc++; qss += per[j]; }
          }
        }
      }
    }
    for (int off = 32; off; off >>= 1) {
      removed += __shfl_down(removed, off);
      qcc += __shfl_down(qcc, off);
      qss += __shfl_down(qss, off);
      anyp |= __shfl_down(anyp, off);
    }
    if (lane == 0) { rrem[wave] = removed; rqc[wave] = qcc; rqs[wave] = qss; rany[wave] = anyp; }
    __syncthreads();
    if (tid == 0) {
      int rm = 0, qct = 0, ap = 0; float qst = 0.f;
      for (int w = 0; w < NW; ++w) { rm += rrem[w]; qct += rqc[w]; qst += rqs[w]; ap |= rany[w]; }
      sh_nact = nact - 1 - rm;
      if (t0_hasrem && ap) {
        push_sum += qst / ((float)qct + EPSF);
        push_cnt += 1.f;
      }
    }
    __syncthreads();
  }

  if (tid == 0) {
    float gate = (n_pos > 1) ? 1.f : 0.f;
    out_bp[b * 2 + 0] = gate * push_sum / (push_cnt + EPSF);
    out_bp[b * 2 + 1] = gate * pull_sum / (pull_cnt + EPSF);
  }
}

// ============================================================== launch =====
extern "C" void kernel_launch(void* const* d_in, const int* in_sizes, int n_in,
                              void* d_out, int out_size, void* d_ws, size_t ws_size,
                              hipStream_t stream) {
  const int* gti = (const int*)d_in[1];
  const float* gtb = (const float*)d_in[2];
  const float* props = (const float*)d_in[3];
  float* out = (float*)d_out;
  const int nb = in_sizes[1] / BN;   // 8

  // ws layout (bytes)
  const size_t off_adj  = 0;                                    // nb*32*2048*8
  const size_t off_box  = off_adj  + (size_t)nb * BN * 64 * 4;  // nb*BN*16
  const size_t off_per  = off_box  + (size_t)nb * BN * 16;      // nb*BN*4
  const size_t off_sc   = off_per  + (size_t)nb * BN * 4;       // nb*BN*4
  const size_t off_qs   = off_sc   + (size_t)nb * BN * 4;       // nb*BN*4
  const size_t off_qc   = off_qs   + (size_t)nb * BN * 4;       // nb*BN*4
  const size_t off_gts  = off_qc   + (size_t)nb * BN * 4;       // nb*BN*2
  const size_t off_ev   = off_gts  + (size_t)nb * BN * 2;       // nb*BN*2
  const size_t off_pm   = off_ev   + (size_t)nb * BN * 2;       // nb*64*4
  const size_t off_fpr  = off_pm   + (size_t)nb * 64 * 4;       // nb*64*4
  const size_t off_hp   = off_fpr  + (size_t)nb * 64 * 4;       // nb*64*4
  const size_t off_meta = off_hp   + (size_t)nb * 64 * 4;       // nb*4*4
  const size_t off_bp   = off_meta + (size_t)nb * 4 * 4;        // nb*2*4
  const size_t needed   = off_bp   + (size_t)nb * 2 * 4;

  if (ws_size >= needed && nb == 8) {
    char* ws = (char*)d_ws;
    uint2* adjC = (uint2*)(ws + off_adj);
    float4* boxs = (float4*)(ws + off_box);
    float* pers = (float*)(ws + off_per);
    float* scs = (float*)(ws + off_sc);
    float* qs = (float*)(ws + off_qs);
    int* qc = (int*)(ws + off_qc);
    short* gtss = (short*)(ws + off_gts);
    unsigned short* ev = (unsigned short*)(ws + off_ev);
    unsigned* pm = (unsigned*)(ws + off_pm);
    int* fpr = (int*)(ws + off_fpr);
    unsigned* hp = (unsigned*)(ws + off_hp);
    int* meta = (int*)(ws + off_meta);
    float* bp = (float*)(ws + off_bp);

    k1_sort<<<nb * 8, 256, 0, stream>>>(gti, gtb, props, boxs, pers, gtss, scs);
    k2_adj<<<nb * 32, 512, 0, stream>>>(boxs, adjC);
    k3a_resolve<<<nb, 256, 0, stream>>>(gtss, adjC, pm, fpr, ev, meta, qs, qc, hp);
    k3b_events<<<nb * 8, 256, 0, stream>>>(gtss, pers, adjC, pm, fpr, meta, qs, qc, hp);
    k3c_loss<<<nb, 256, 0, stream>>>(boxs, scs, gtss, ev, fpr, meta, qs, qc, hp, bp);
    nms_finalize_kernel<<<1, 64, 0, stream>>>(bp, out, nb);
  } else {
    float* bp = (float*)d_ws;
    nms_loss_kernel<<<nb, NT, 0, stream>>>(gti, gtb, props, bp);
    nms_finalize_kernel<<<1, 64, 0, stream>>>(bp, out, nb);
  }
}

// Round 10
// 82.963 us; speedup vs baseline: 1.6115x; 1.1846x over previous
//
#include <hip/hip_runtime.h>
#include <math.h>
#include <limits.h>

#define EPSF 1e-6f
#define THR 0.5f
#define PUSH_W 1.0f
#define PULL_W 1.0f

constexpr int BN = 2048;    // proposals per batch
constexpr int BG = 64;      // gt boxes per batch

__device__ __forceinline__ float iou_box(float4 a, float4 b) {
  float aa = (a.z - a.x) * (a.w - a.y);
  float ab = (b.z - b.x) * (b.w - b.y);
  float w = fmaxf(fminf(a.z, b.z) - fmaxf(a.x, b.x), 0.f);
  float h = fmaxf(fminf(a.w, b.w) - fmaxf(a.y, b.y), 0.f);
  float inter = w * h;
  return inter / (aa + ab - inter + EPSF);
}

// -------------------------------------------------- K1: rank-by-count sort
__global__ __launch_bounds__(256) void k1_sort(
    const int* __restrict__ gti_all, const float* __restrict__ gtb_all,
    const float* __restrict__ prop_all,
    float4* __restrict__ boxs, float* __restrict__ pers,
    short* __restrict__ gtss, float* __restrict__ scs)
{
  const int b = blockIdx.x & 7;        // batch
  const int rg = blockIdx.x >> 3;      // row group
  const int tid = threadIdx.x;
  __shared__ unsigned long long key[BN];   // 16 KB

  const float* P = prop_all + (size_t)b * BN * 5;
  const int* gti = gti_all + b * BN;
  const float* GB = gtb_all + b * BG * 4;

  for (int k = 0; k < 8; ++k) {
    int j = tid + k * 256;
    unsigned bits = __float_as_uint(P[j * 5 + 4]);
    key[j] = ((unsigned long long)bits << 32) | (unsigned)(BN - 1 - j);
  }
  __syncthreads();

  const int r = rg * 256 + tid;
  const unsigned long long myk = key[r];
  int rank = 0;
  const ulonglong2* K2 = (const ulonglong2*)key;
#pragma unroll 8
  for (int j = 0; j < BN / 2; ++j) {
    ulonglong2 kk = K2[j];
    rank += (kk.x > myk) ? 1 : 0;
    rank += (kk.y > myk) ? 1 : 0;
  }

  int idx = (BN - 1) - (int)(myk & 0xffffffffu);
  float x1 = P[idx * 5 + 0], y1 = P[idx * 5 + 1];
  float x2 = P[idx * 5 + 2], y2 = P[idx * 5 + 3];
  float s = __uint_as_float((unsigned)(myk >> 32));
  int g = gti[idx];
  float4 bx = make_float4(x1, y1, x2, y2);
  boxs[b * BN + rank] = bx;
  scs[b * BN + rank] = s;
  gtss[b * BN + rank] = (short)g;
  float pv = 0.f;
  if (g >= 0) {
    float4 gb = make_float4(GB[g * 4 + 0], GB[g * 4 + 1], GB[g * 4 + 2], GB[g * 4 + 3]);
    float i2 = iou_box(gb, bx);
    pv = -logf(EPSF + i2) * s;
  }
  pers[b * BN + rank] = pv;
}

// ------------------------------------------------------------- K2: adjacency
// R=4 rows/lane in VGPRs; 8 KB column tile in LDS; one broadcast ds_read
// feeds 4 IoUs. Branchless predicate: iou>0.5 <=> 3*inter > aa+ab+eps.
// grid = b(8) x rg(8) x cg(4); wave w = chunk c = cg*8+w (64 cols).
__global__ __launch_bounds__(512) void k2_adj(
    const float4* __restrict__ boxs, uint2* __restrict__ adjC)
{
  const int b  = blockIdx.x & 7;
  const int rg = (blockIdx.x >> 3) & 7;
  const int cg = blockIdx.x >> 6;        // 0..3
  const int tid = threadIdx.x;           // 0..511
  const int lane = tid & 63;
  const int w = tid >> 6;                // wave 0..7
  __shared__ float4 bs[512];             // 8 KB column tile

  const float4* B = boxs + b * BN;
  bs[tid] = B[cg * 512 + tid];

  const float4 r0 = B[rg * 256 +   0 + lane];
  const float4 r1 = B[rg * 256 +  64 + lane];
  const float4 r2 = B[rg * 256 + 128 + lane];
  const float4 r3 = B[rg * 256 + 192 + lane];
  const float a0 = (r0.z - r0.x) * (r0.w - r0.y) + EPSF;
  const float a1 = (r1.z - r1.x) * (r1.w - r1.y) + EPSF;
  const float a2 = (r2.z - r2.x) * (r2.w - r2.y) + EPSF;
  const float a3 = (r3.z - r3.x) * (r3.w - r3.y) + EPSF;
  __syncthreads();

  const float4* C = &bs[w * 64];
  unsigned lo0 = 0, lo1 = 0, lo2 = 0, lo3 = 0;
  unsigned hi0 = 0, hi1 = 0, hi2 = 0, hi3 = 0;

#define PRED(RR, AA, BJ, AB)                                              \
  (3.0f * (fmaxf(fminf(RR.z, BJ.z) - fmaxf(RR.x, BJ.x), 0.f) *            \
           fmaxf(fminf(RR.w, BJ.w) - fmaxf(RR.y, BJ.y), 0.f)) > AA + AB)

#pragma unroll 8
  for (int jj = 0; jj < 32; ++jj) {
    float4 bj = C[jj];                   // wave-uniform -> LDS broadcast
    float ab = (bj.z - bj.x) * (bj.w - bj.y);
    lo0 |= PRED(r0, a0, bj, ab) ? (1u << jj) : 0u;
    lo1 |= PRED(r1, a1, bj, ab) ? (1u << jj) : 0u;
    lo2 |= PRED(r2, a2, bj, ab) ? (1u << jj) : 0u;
    lo3 |= PRED(r3, a3, bj, ab) ? (1u << jj) : 0u;
  }
#pragma unroll 8
  for (int jj = 0; jj < 32; ++jj) {
    float4 bj = C[32 + jj];
    float ab = (bj.z - bj.x) * (bj.w - bj.y);
    hi0 |= PRED(r0, a0, bj, ab) ? (1u << jj) : 0u;
    hi1 |= PRED(r1, a1, bj, ab) ? (1u << jj) : 0u;
    hi2 |= PRED(r2, a2, bj, ab) ? (1u << jj) : 0u;
    hi3 |= PRED(r3, a3, bj, ab) ? (1u << jj) : 0u;
  }
#undef PRED

  const int c = cg * 8 + w;
  uint2* CO = adjC + ((size_t)b * 32 + c) * 2048;
  CO[rg * 256 +   0 + lane] = make_uint2(lo0, hi0);
  CO[rg * 256 +  64 + lane] = make_uint2(lo1, hi1);
  CO[rg * 256 + 128 + lane] = make_uint2(lo2, hi2);
  CO[rg * 256 + 192 + lane] = make_uint2(lo3, hi3);
}

// ------------------------- K3a: streaming-sup greedy resolve (1 wave/batch)
// 3-deep register prefetch (round-8 version, proven): chunk c uses buf[c%3].
__global__ __launch_bounds__(64, 1) void k3a_resolve(
    const short* __restrict__ gtss, const uint2* __restrict__ adjC,
    unsigned* __restrict__ pm_g, int* __restrict__ fpr_g,
    unsigned short* __restrict__ ev_g, int* __restrict__ meta_g,
    float* __restrict__ qs_g, int* __restrict__ qc_g, unsigned* __restrict__ hp_g,
    int* __restrict__ arrive)
{
  const int b = blockIdx.x;
  const int lane = threadIdx.x;       // 0..63
  __shared__ unsigned pm_lds[64];
  __shared__ int fpr_s[64];

  if (lane == 0) *arrive = 0;         // reset k3c's arrive counter (all blocks write 0)

  const uint2* Cb = adjC + (size_t)b * 32 * 2048;

  unsigned act = 0;
#pragma unroll
  for (int k = 0; k < 32; ++k)
    if (gtss[b * BN + k * 64 + lane] >= 0) act |= (1u << k);
  int npos = __popc(act);
  for (int o = 1; o < 64; o <<= 1) npos += __shfl_xor(npos, o);

  unsigned sup = 0;
  unsigned mypm = 0;
  int npick = 0;                      // wave-uniform

  uint2 bufA[32], bufB[32], bufC[32];
#pragma unroll
  for (int k = 0; k < 32; ++k) bufA[k] = Cb[(size_t)0 * 2048 + k * 64 + lane];
#pragma unroll
  for (int k = 0; k < 32; ++k) bufB[k] = Cb[(size_t)1 * 2048 + k * 64 + lane];
#pragma unroll
  for (int k = 0; k < 32; ++k) bufC[k] = Cb[(size_t)2 * 2048 + k * 64 + lane];

#define CHUNK(cc, BUF)                                                         \
  {                                                                            \
    unsigned mybit = ((act >> (cc)) & ~(sup >> (cc))) & 1u;                    \
    unsigned long long row64 =                                                 \
        ((unsigned long long)BUF[cc].y << 32) | (unsigned long long)BUF[cc].x; \
    unsigned long long pickw = 0ull;                                           \
    unsigned long long bal = __ballot(mybit != 0u);                            \
    while (bal) {                                                              \
      int bpos = (int)__ffsll(bal) - 1;                                        \
      pickw |= 1ull << bpos;                                                   \
      mybit &= ~(unsigned)((row64 >> bpos) & 1ull);                            \
      bal = __ballot(mybit != 0u);                                             \
    }                                                                          \
    if (pickw != 0ull) {                                                       \
      npick += (int)__popcll(pickw);                                           \
      unsigned pwlo = (unsigned)pickw;                                         \
      unsigned pwhi = (unsigned)(pickw >> 32);                                 \
      if (lane == 0) { pm_lds[2*(cc)] = pwlo; pm_lds[2*(cc)+1] = pwhi; }       \
      _Pragma("unroll")                                                        \
      for (int k = 0; k < 32; ++k) {                                           \
        unsigned hit = (BUF[k].x & pwlo) | (BUF[k].y & pwhi);                  \
        sup |= (hit != 0u) ? (1u << k) : 0u;                                   \
      }                                                                        \
    } else if (lane == 0) {                                                    \
      pm_lds[2*(cc)] = 0u; pm_lds[2*(cc)+1] = 0u;                              \
    }                                                                          \
    if ((cc) + 3 < 32) {                                                       \
      _Pragma("unroll")                                                        \
      for (int k = 0; k < 32; ++k)                                             \
        BUF[k] = Cb[(size_t)((cc) + 3) * 2048 + k * 64 + lane];                \
    }                                                                          \
  }

  CHUNK(0, bufA)  CHUNK(1, bufB)  CHUNK(2, bufC)  CHUNK(3, bufA)
  CHUNK(4, bufB)  CHUNK(5, bufC)  CHUNK(6, bufA)  CHUNK(7, bufB)
  CHUNK(8, bufC)  CHUNK(9, bufA)  CHUNK(10, bufB) CHUNK(11, bufC)
  CHUNK(12, bufA) CHUNK(13, bufB) CHUNK(14, bufC) CHUNK(15, bufA)
  CHUNK(16, bufB) CHUNK(17, bufC) CHUNK(18, bufA) CHUNK(19, bufB)
  CHUNK(20, bufC) CHUNK(21, bufA) CHUNK(22, bufB) CHUNK(23, bufC)
  CHUNK(24, bufA) CHUNK(25, bufB) CHUNK(26, bufC) CHUNK(27, bufA)
  CHUNK(28, bufB) CHUNK(29, bufC) CHUNK(30, bufA) CHUNK(31, bufB)
#undef CHUNK

  fpr_s[lane] = INT_MAX;
  __syncthreads();

  // epilogue: prefix popcounts, ev2rank, fpr
  mypm = pm_lds[lane];                // word covers ranks lane*32..+31
  int pre = 0;
  for (int w = 0; w < lane; ++w) pre += __popc(pm_lds[w]);
  {
    unsigned w = mypm; int e = pre;
    while (w) {
      int bpos = __ffs(w) - 1; w &= w - 1;
      int rank = lane * 32 + bpos;
      ev_g[b * BN + e] = (unsigned short)rank;
      int g = (int)gtss[b * BN + rank];
      atomicMin(&fpr_s[g], rank);
      e++;
    }
  }
  __syncthreads();

  pm_g[b * 64 + lane] = mypm;
  fpr_g[b * 64 + lane] = fpr_s[lane];
  hp_g[b * 64 + lane] = 0u;
  if (lane == 0) {
    meta_g[b * 4 + 0] = npick;
    meta_g[b * 4 + 1] = 0;        // lastrem
    meta_g[b * 4 + 2] = npos;
  }
  for (int k = 0; k < 32; ++k) {
    int j = lane + k * 64;
    qs_g[b * BN + j] = 0.f;
    qc_g[b * BN + j] = 0;
  }
}

// ---------------------------- K3b: parallel per-box event contributions
__global__ __launch_bounds__(256) void k3b_events(
    const short* __restrict__ gtss, const float* __restrict__ pers,
    const uint2* __restrict__ adjC, const unsigned* __restrict__ pm_g,
    const int* __restrict__ fpr_g, int* __restrict__ meta_g,
    float* __restrict__ qs_g, int* __restrict__ qc_g, unsigned* __restrict__ hp_g)
{
  const int blk = blockIdx.x;       // 8 batches * 8 segments
  const int b = blk & 7;
  const int seg = blk >> 3;
  const int tid = threadIdx.x;
  __shared__ unsigned pm_s[64];
  __shared__ unsigned pre_s[64];
  __shared__ short gts_s[BN];       // 4 KB

  if (tid < 64) pm_s[tid] = pm_g[b * 64 + tid];
  for (int k = 0; k < 4; ++k)
    ((int*)gts_s)[tid + 256 * k] = ((const int*)(gtss + b * BN))[tid + 256 * k];
  __syncthreads();
  if (tid < 64) {
    int s = 0;
    for (int w = 0; w < tid; ++w) s += __popc(pm_s[w]);
    pre_s[tid] = (unsigned)s;
  }
  __syncthreads();

  const int j = seg * 256 + tid;
  const uint2* Cj = adjC + (size_t)b * 32 * 2048 + j;
  int frank = -1;
#pragma unroll
  for (int c = 0; c < 32; ++c) {
    uint2 v = Cj[(size_t)c * 2048];
    unsigned m0 = v.x & pm_s[2 * c];
    unsigned m1 = v.y & pm_s[2 * c + 1];
    if (frank < 0 && m0) frank = c * 64 + __ffs(m0) - 1;
    if (frank < 0 && m1) frank = c * 64 + 32 + __ffs(m1) - 1;
  }

  int gj = (int)gts_s[j];
  if (frank >= 0 && frank != j && gj >= 0) {
    int e = (int)pre_s[frank >> 5] + __popc(pm_s[frank >> 5] & ((1u << (frank & 31)) - 1u));
    int P = meta_g[b * 4 + 0];
    if (e == P - 1) atomicOr(&meta_g[b * 4 + 1], 1);
    int gt = (int)gts_s[frank];
    if (gj != gt) {
      atomicOr(&hp_g[b * 64 + (e >> 5)], 1u << (e & 31));
      if (fpr_g[b * 64 + gj] > frank) {
        atomicAdd(&qs_g[b * BN + e], pers[b * BN + j]);
        atomicAdd(&qc_g[b * BN + e], 1);
      }
    }
  }
}

// -------------- K3c: event pass (block/batch) + fused final average
__global__ __launch_bounds__(256) void k3c_loss(
    const float4* __restrict__ boxs, const float* __restrict__ scs,
    const short* __restrict__ gtss, const unsigned short* __restrict__ ev_g,
    const int* __restrict__ fpr_g, const int* __restrict__ meta_g,
    const float* __restrict__ qs_g, const int* __restrict__ qc_g,
    const unsigned* __restrict__ hp_g, float* __restrict__ bp,
    int* __restrict__ arrive, float* __restrict__ out, int nb)
{
  const int b = blockIdx.x;
  const int tid = threadIdx.x;
  const int lane = tid & 63;
  const int wave = tid >> 6;
  __shared__ float redp[4][4];

  const int P = meta_g[b * 4 + 0];
  const int lastrem = meta_g[b * 4 + 1];
  const int npos = meta_g[b * 4 + 2];
  float pull_l = 0.f, pcl = 0.f, push_l = 0.f, pshl = 0.f;
  for (int t = tid; t < P; t += 256) {
    int r = (int)ev_g[b * BN + t];
    int g = (int)gtss[b * BN + r];
    int fp = fpr_g[b * 64 + g];
    bool seen = (fp < r);
    bool hr = (t < P - 1) || (lastrem != 0);
    if (seen) {
      pcl += 1.f;
      if (hr) {
        float4 bA = boxs[b * BN + fp];
        float4 bB = boxs[b * BN + r];
        float io = iou_box(bA, bB);
        pull_l += -logf(1.f - THR + fmaxf(io, EPSF)) * scs[b * BN + r];
      }
    }
    if (hr && ((hp_g[b * 64 + (t >> 5)] >> (t & 31)) & 1u)) {
      pshl += 1.f;
      push_l += qs_g[b * BN + t] / ((float)qc_g[b * BN + t] + EPSF);
    }
  }
  for (int o = 1; o < 64; o <<= 1) {
    pull_l += __shfl_xor(pull_l, o);
    pcl    += __shfl_xor(pcl, o);
    push_l += __shfl_xor(push_l, o);
    pshl   += __shfl_xor(pshl, o);
  }
  if (lane == 0) { redp[wave][0] = pull_l; redp[wave][1] = pcl; redp[wave][2] = push_l; redp[wave][3] = pshl; }
  __syncthreads();
  if (tid == 0) {
    float Ps = 0.f, Pc = 0.f, Ss = 0.f, Sc = 0.f;
    for (int w = 0; w < 4; ++w) { Ps += redp[w][0]; Pc += redp[w][1]; Ss += redp[w][2]; Sc += redp[w][3]; }
    float gate = (npos > 1) ? 1.f : 0.f;
    bp[b * 2 + 0] = gate * Ss / (Sc + EPSF);   // push
    bp[b * 2 + 1] = gate * Ps / (Pc + EPSF);   // pull
    __threadfence();
    int old = atomicAdd(arrive, 1);
    if (old == nb - 1) {                        // last block finalizes
      __threadfence();
      float ps = 0.f, pl = 0.f;
      for (int i = 0; i < nb; ++i) { ps += bp[2 * i]; pl += bp[2 * i + 1]; }
      float inv = 1.f / (float)nb;
      out[0] = ps * inv * PUSH_W;
      out[1] = pl * inv * PULL_W;
      *arrive = 0;                              // reset for next replay
    }
  }
}

// =============================== fallback path (round-1 kernel, proven) =====
constexpr int NT = 256;
constexpr int PT = BN / NT;
constexpr int NW = NT / 64;

__global__ void nms_finalize_kernel(const float* __restrict__ bp, float* __restrict__ out, int nb) {
  if (threadIdx.x == 0 && blockIdx.x == 0) {
    float ps = 0.f, pl = 0.f;
    for (int b = 0; b < nb; ++b) { ps += bp[2 * b]; pl += bp[2 * b + 1]; }
    float inv = 1.f / (float)nb;
    out[0] = ps * inv * PUSH_W;
    out[1] = pl * inv * PULL_W;
  }
}

__global__ __launch_bounds__(NT) void nms_loss_kernel(
    const int* __restrict__ gti_all, const float* __restrict__ gtb_all,
    const float* __restrict__ prop_all, float* __restrict__ out_bp)
{
  const int b = blockIdx.x;
  const int tid = threadIdx.x;
  const int lane = tid & 63;
  const int wave = tid >> 6;

  __shared__ float4 box[BN];
  __shared__ float sc[BN];
  __shared__ float per[BN];
  __shared__ int gts[BN];
  __shared__ unsigned char act[BN];
  __shared__ int rec[BG];
  __shared__ float rs[NW];
  __shared__ int ri[NW];
  __shared__ int rrem[NW];
  __shared__ int rqc[NW];
  __shared__ float rqs[NW];
  __shared__ int rany[NW];
  __shared__ int sh_nact;
  __shared__ int sh_ig;
  __shared__ float4 sh_ibox;

  const int* gti = gti_all + b * BN;
  const float* GB = gtb_all + b * BG * 4;
  const float* P = prop_all + (size_t)b * BN * 5;

  int local_pos = 0;
  for (int k = 0; k < PT; ++k) {
    int j = tid + k * NT;
    float x1 = P[j * 5 + 0], y1 = P[j * 5 + 1];
    float x2 = P[j * 5 + 2], y2 = P[j * 5 + 3];
    float s = P[j * 5 + 4];
    box[j] = make_float4(x1, y1, x2, y2);
    sc[j] = s;
    int g = gti[j];
    gts[j] = g;
    unsigned char a = (g >= 0) ? 1 : 0;
    act[j] = a;
    local_pos += a;
    float pv = 0.f;
    if (g >= 0) {
      float4 gb = make_float4(GB[g * 4], GB[g * 4 + 1], GB[g * 4 + 2], GB[g * 4 + 3]);
      float i2 = iou_box(gb, make_float4(x1, y1, x2, y2));
      pv = -logf(EPSF + i2) * s;
    }
    per[j] = pv;
  }
  if (tid < BG) rec[tid] = -1;
  for (int off = 32; off; off >>= 1) local_pos += __shfl_down(local_pos, off);
  if (lane == 0) rrem[wave] = local_pos;
  __syncthreads();
  int n_pos = 0;
  if (tid == 0) {
    for (int w = 0; w < NW; ++w) n_pos += rrem[w];
    sh_nact = n_pos;
  }
  float pull_sum = 0.f, push_sum = 0.f, pull_cnt = 0.f, push_cnt = 0.f;
  int t0_hasrem = 0;
  __syncthreads();

  while (true) {
    int nact = sh_nact;
    if (nact <= 0) break;
    float bs = -INFINITY;
    int bi = BN;
    for (int k = 0; k < PT; ++k) {
      int j = tid + k * NT;
      if (act[j]) {
        float s = sc[j];
        if (s > bs || (s == bs && j < bi)) { bs = s; bi = j; }
      }
    }
    for (int off = 32; off; off >>= 1) {
      float os = __shfl_down(bs, off);
      int oi = __shfl_down(bi, off);
      if (os > bs || (os == bs && oi < bi)) { bs = os; bi = oi; }
    }
    if (lane == 0) { rs[wave] = bs; ri[wave] = bi; }
    __syncthreads();
    if (tid == 0) {
      float cs = rs[0]; int ci = ri[0];
      for (int w = 1; w < NW; ++w)
        if (rs[w] > cs || (rs[w] == cs && ri[w] < ci)) { cs = rs[w]; ci = ri[w]; }
      int i = ci;
      int ig = gts[i];
      act[i] = 0;
      t0_hasrem = (nact - 1 > 0);
      int r = rec[ig];
      if (r >= 0) {
        pull_cnt += 1.f;
        if (t0_hasrem) {
          float i2 = iou_box(box[r], box[i]);
          float m = fmaxf(i2, EPSF);
          pull_sum += -logf(1.f - THR + m) * sc[i];
        }
      } else {
        rec[ig] = i;
      }
      sh_ig = ig; sh_ibox = box[i];
    }
    __syncthreads();
    float4 ib = sh_ibox;
    int igx = sh_ig;
    int removed = 0, qcc = 0, anyp = 0;
    float qss = 0.f;
    for (int k = 0; k < PT; ++k) {
      int j = tid + k * NT;
      if (act[j]) {
        float i2 = iou_box(ib, box[j]);
        if (i2 > THR) {
          act[j] = 0;
          removed++;
          int gj = gts[j];
          if (gj != igx) {
            anyp = 1;
            if (rec[gj] < 0) { qcc++; qss += per[j]; }
          }
        }
      }
    }
    for (int off = 32; off; off >>= 1) {
      removed += __shfl_down(removed, off);
      qcc += __shfl_down(qcc, off);
      qss += __shfl_down(qss, off);
      anyp |= __shfl_down(anyp, off);
    }
    if (lane == 0) { rrem[wave] = removed; rqc[wave] = qcc; rqs[wave] = qss; rany[wave] = anyp; }
    __syncthreads();
    if (tid == 0) {
      int rm = 0, qct = 0, ap = 0; float qst = 0.f;
      for (int w = 0; w < NW; ++w) { rm += rrem[w]; qct += rqc[w]; qst += rqs[w]; ap |= rany[w]; }
      sh_nact = nact - 1 - rm;
      if (t0_hasrem && ap) {
        push_sum += qst / ((float)qct + EPSF);
        push_cnt += 1.f;
      }
    }
    __syncthreads();
  }

  if (tid == 0) {
    float gate = (n_pos > 1) ? 1.f : 0.f;
    out_bp[b * 2 + 0] = gate * push_sum / (push_cnt + EPSF);
    out_bp[b * 2 + 1] = gate * pull_sum / (pull_cnt + EPSF);
  }
}

// ============================================================== launch =====
extern "C" void kernel_launch(void* const* d_in, const int* in_sizes, int n_in,
                              void* d_out, int out_size, void* d_ws, size_t ws_size,
                              hipStream_t stream) {
  const int* gti = (const int*)d_in[1];
  const float* gtb = (const float*)d_in[2];
  const float* props = (const float*)d_in[3];
  float* out = (float*)d_out;
  const int nb = in_sizes[1] / BN;   // 8

  // ws layout (bytes)
  const size_t off_adj  = 0;                                    // nb*32*2048*8
  const size_t off_box  = off_adj  + (size_t)nb * BN * 64 * 4;  // nb*BN*16
  const size_t off_per  = off_box  + (size_t)nb * BN * 16;      // nb*BN*4
  const size_t off_sc   = off_per  + (size_t)nb * BN * 4;       // nb*BN*4
  const size_t off_qs   = off_sc   + (size_t)nb * BN * 4;       // nb*BN*4
  const size_t off_qc   = off_qs   + (size_t)nb * BN * 4;       // nb*BN*4
  const size_t off_gts  = off_qc   + (size_t)nb * BN * 4;       // nb*BN*2
  const size_t off_ev   = off_gts  + (size_t)nb * BN * 2;       // nb*BN*2
  const size_t off_pm   = off_ev   + (size_t)nb * BN * 2;       // nb*64*4
  const size_t off_fpr  = off_pm   + (size_t)nb * 64 * 4;       // nb*64*4
  const size_t off_hp   = off_fpr  + (size_t)nb * 64 * 4;       // nb*64*4
  const size_t off_meta = off_hp   + (size_t)nb * 64 * 4;       // nb*4*4
  const size_t off_bp   = off_meta + (size_t)nb * 4 * 4;        // nb*2*4
  const size_t off_arr  = off_bp   + (size_t)nb * 2 * 4;        // 4
  const size_t needed   = off_arr + 64;

  if (ws_size >= needed && nb == 8) {
    char* ws = (char*)d_ws;
    uint2* adjC = (uint2*)(ws + off_adj);
    float4* boxs = (float4*)(ws + off_box);
    float* pers = (float*)(ws + off_per);
    float* scs = (float*)(ws + off_sc);
    float* qs = (float*)(ws + off_qs);
    int* qc = (int*)(ws + off_qc);
    short* gtss = (short*)(ws + off_gts);
    unsigned short* ev = (unsigned short*)(ws + off_ev);
    unsigned* pm = (unsigned*)(ws + off_pm);
    int* fpr = (int*)(ws + off_fpr);
    unsigned* hp = (unsigned*)(ws + off_hp);
    int* meta = (int*)(ws + off_meta);
    float* bp = (float*)(ws + off_bp);
    int* arrive = (int*)(ws + off_arr);

    k1_sort<<<nb * 8, 256, 0, stream>>>(gti, gtb, props, boxs, pers, gtss, scs);
    k2_adj<<<nb * 32, 512, 0, stream>>>(boxs, adjC);
    k3a_resolve<<<nb, 64, 0, stream>>>(gtss, adjC, pm, fpr, ev, meta, qs, qc, hp, arrive);
    k3b_events<<<nb * 8, 256, 0, stream>>>(gtss, pers, adjC, pm, fpr, meta, qs, qc, hp);
    k3c_loss<<<nb, 256, 0, stream>>>(boxs, scs, gtss, ev, fpr, meta, qs, qc, hp, bp, arrive, out, nb);
  } else {
    float* bp = (float*)d_ws;
    nms_loss_kernel<<<nb, NT, 0, stream>>>(gti, gtb, props, bp);
    nms_finalize_kernel<<<1, 64, 0, stream>>>(bp, out, nb);
  }
}